// Round 6
// baseline (582.901 us; speedup 1.0000x reference)
//
#include <hip/hip_runtime.h>
#include <hip/hip_bf16.h>
#include <math.h>

#define BB 2
#define SS 2048
#define DIM 1024
#define NH 16
#define DH 64

typedef __bf16 bf16x8 __attribute__((ext_vector_type(8)));
typedef __bf16 bf16x4 __attribute__((ext_vector_type(4)));
typedef short s16x4 __attribute__((ext_vector_type(4)));
typedef float f32x4 __attribute__((ext_vector_type(4)));

__device__ __forceinline__ void glds16(const __hip_bfloat16* g, __hip_bfloat16* l) {
    __builtin_amdgcn_global_load_lds(
        (const __attribute__((address_space(1))) void*)g,
        (__attribute__((address_space(3))) void*)l, 16, 0, 0);
}

// fast fp32 -> bf16 (round-half-up, finite inputs): 2 VALU ops
__device__ __forceinline__ unsigned short f2bf(float x) {
    unsigned int u = __builtin_bit_cast(unsigned int, x);
    return (unsigned short)((u + 0x8000u) >> 16);
}

// ---------------- prep: split fp32 -> bf16 hi + lo ----------------
__global__ void split_f32(const float4* __restrict__ in,
                          ushort4* __restrict__ hi, ushort4* __restrict__ lo) {
    int i = blockIdx.x * 256 + threadIdx.x;
    float4 v = in[i];
    ushort4 h, l;
    __hip_bfloat16 t;
    t = __float2bfloat16(v.x); h.x = *(ushort*)&t; t = __float2bfloat16(v.x - __bfloat162float(t)); l.x = *(ushort*)&t;
    t = __float2bfloat16(v.y); h.y = *(ushort*)&t; t = __float2bfloat16(v.y - __bfloat162float(t)); l.y = *(ushort*)&t;
    t = __float2bfloat16(v.z); h.z = *(ushort*)&t; t = __float2bfloat16(v.z - __bfloat162float(t)); l.z = *(ushort*)&t;
    t = __float2bfloat16(v.w); h.w = *(ushort*)&t; t = __float2bfloat16(v.w - __bfloat162float(t)); l.w = *(ushort*)&t;
    hi[i] = h; lo[i] = l;
}

// ------- prep: transpose all 4 W [K,N] -> [N,K], split hi/lo (one launch) -------
__global__ void trans_split4(const float* __restrict__ Wq, const float* __restrict__ Wk,
                             const float* __restrict__ Wv, const float* __restrict__ Wo,
                             __hip_bfloat16* __restrict__ T3hi, __hip_bfloat16* __restrict__ T3lo,
                             __hip_bfloat16* __restrict__ Tohi, __hip_bfloat16* __restrict__ Tolo) {
    int z = blockIdx.z;
    const float* W = (z == 0) ? Wq : (z == 1) ? Wk : (z == 2) ? Wv : Wo;
    __hip_bfloat16* Thi = (z < 3) ? T3hi + (size_t)z * DIM * DIM : Tohi;
    __hip_bfloat16* Tlo = (z < 3) ? T3lo + (size_t)z * DIM * DIM : Tolo;
    __shared__ float tile[32][33];
    int k0 = blockIdx.x * 32, n0 = blockIdx.y * 32;
    int t = threadIdx.x;
    int r = t >> 3, c = (t & 7) << 2;
    float4 v = *(const float4*)&W[(size_t)(k0 + r) * DIM + n0 + c];
    tile[r][c] = v.x; tile[r][c + 1] = v.y; tile[r][c + 2] = v.z; tile[r][c + 3] = v.w;
    __syncthreads();
    size_t base = (size_t)(n0 + r) * DIM + k0 + c;
#pragma unroll
    for (int i = 0; i < 4; ++i) {
        float x = tile[c + i][r];
        __hip_bfloat16 h = __float2bfloat16(x);
        Thi[base + i] = h;
        Tlo[base + i] = __float2bfloat16(x - __bfloat162float(h));
    }
}

// ---------------- split-bf16 3-term MFMA GEMM (unchanged) ----------------
#define BM 128
#define BN 64
#define BK 32
__global__ __launch_bounds__(256) void gemm3term(
    const __hip_bfloat16* __restrict__ Ahi, const __hip_bfloat16* __restrict__ Alo,
    const __hip_bfloat16* __restrict__ Bhi, const __hip_bfloat16* __restrict__ Blo,
    const float* __restrict__ b0, const float* __restrict__ b1, const float* __restrict__ b2,
    __hip_bfloat16* __restrict__ oq, __hip_bfloat16* __restrict__ ok,
    __hip_bfloat16* __restrict__ ov, float* __restrict__ of32, int mode) {
    __shared__ alignas(16) __hip_bfloat16 sAh[BM * BK];
    __shared__ alignas(16) __hip_bfloat16 sAl[BM * BK];
    __shared__ alignas(16) __hip_bfloat16 sBh[BN * BK];
    __shared__ alignas(16) __hip_bfloat16 sBl[BN * BK];
    const int K = 1024;
    int tid = threadIdx.x;
    int wave = tid >> 6, lane = tid & 63, quad = lane >> 4, l16 = lane & 15;
    int m0 = blockIdx.y * BM, n0 = blockIdx.x * BN;
    int mo = (wave >> 1) * 64, no = (wave & 1) * 32;

    f32x4 acc[4][2];
#pragma unroll
    for (int i = 0; i < 4; ++i)
#pragma unroll
        for (int j = 0; j < 2; ++j) acc[i][j] = (f32x4){0.f, 0.f, 0.f, 0.f};

    int ar = tid >> 2;
    int ac = (tid & 3) << 3;
    const __hip_bfloat16* gAh = Ahi + (size_t)(m0 + ar) * K + ac;
    const __hip_bfloat16* gAl = Alo + (size_t)(m0 + ar) * K + ac;
    const __hip_bfloat16* gBh = Bhi + (size_t)(n0 + ar) * K + ac;
    const __hip_bfloat16* gBl = Blo + (size_t)(n0 + ar) * K + ac;
    __hip_bfloat16* lAh0 = &sAh[ar * BK + ac];
    __hip_bfloat16* lAh1 = &sAh[(ar + 64) * BK + ac];
    __hip_bfloat16* lAl0 = &sAl[ar * BK + ac];
    __hip_bfloat16* lAl1 = &sAl[(ar + 64) * BK + ac];
    __hip_bfloat16* lBh  = &sBh[ar * BK + ac];
    __hip_bfloat16* lBl  = &sBl[ar * BK + ac];

    for (int k0 = 0; k0 < K; k0 += BK) {
        __syncthreads();
        glds16(gAh + k0, lAh0);
        glds16(gAh + (size_t)64 * K + k0, lAh1);
        glds16(gAl + k0, lAl0);
        glds16(gAl + (size_t)64 * K + k0, lAl1);
        glds16(gBh + k0, lBh);
        glds16(gBl + k0, lBl);
        __syncthreads();

        bf16x8 a_h[4], a_l[4], b_h[2], b_l[2];
#pragma unroll
        for (int i = 0; i < 4; ++i) {
            int off = (mo + i * 16 + l16) * BK + quad * 8;
            a_h[i] = *(const bf16x8*)&sAh[off];
            a_l[i] = *(const bf16x8*)&sAl[off];
        }
#pragma unroll
        for (int j = 0; j < 2; ++j) {
            int off = (no + j * 16 + l16) * BK + quad * 8;
            b_h[j] = *(const bf16x8*)&sBh[off];
            b_l[j] = *(const bf16x8*)&sBl[off];
        }
#pragma unroll
        for (int i = 0; i < 4; ++i)
#pragma unroll
            for (int j = 0; j < 2; ++j) {
                acc[i][j] = __builtin_amdgcn_mfma_f32_16x16x32_bf16(a_h[i], b_h[j], acc[i][j], 0, 0, 0);
                acc[i][j] = __builtin_amdgcn_mfma_f32_16x16x32_bf16(a_h[i], b_l[j], acc[i][j], 0, 0, 0);
                acc[i][j] = __builtin_amdgcn_mfma_f32_16x16x32_bf16(a_l[i], b_h[j], acc[i][j], 0, 0, 0);
            }
    }

    int which = (mode == 1) ? (n0 >> 10) : 0;
    const float* bp = (mode == 0) ? b0 : (which == 0) ? b0 : (which == 1) ? b1 : b2;
#pragma unroll
    for (int i = 0; i < 4; ++i)
#pragma unroll
        for (int j = 0; j < 2; ++j) {
            int gmb = m0 + mo + i * 16 + quad * 4;
            int gn  = n0 + no + j * 16 + l16;
            int nn  = gn & 1023;
            float bb = bp[(mode == 0) ? gn : nn];
#pragma unroll
            for (int r = 0; r < 4; ++r) {
                int gm = gmb + r;
                float v = acc[i][j][r] + bb;
                if (mode == 0) {
                    of32[(size_t)gm * 1024 + gn] = v;
                } else {
                    int b = gm >> 11, s = gm & 2047, h = nn >> 6, d = nn & 63;
                    if (which == 0)
                        oq[(((size_t)(b * NH + h)) * SS + s) * DH + d] = __float2bfloat16(v);
                    else if (which == 1)
                        ok[(((size_t)(b * NH + h)) * SS + s) * DH + d] = __float2bfloat16(v);
                    else
                        ov[(((size_t)(b * NH + h)) * DH + d) * SS + s] = __float2bfloat16(v);
                }
            }
        }
}

// -------- flash v4: transposed (S^T) pipeline, register-only P, no LDS --------
// S^T = MFMA16x16x32(A=K_frag, B=Q_frag): C-layout row=key=quad*4+r, col=query=l16.
// P^T = exp2(S^T*SC - pen)  ->  directly the B-operand (k=quad*4+j, n=l16) of
// mfma_f32_16x16x16bf16_1k.  O^T[d][q] += MFMA16(A=Vt_frag, B=P^T).
// Outputs: Op [B,H,DH,S] bf16 (unnormalized), lp [B*H,S] f32 row sums.
__global__ __launch_bounds__(256, 6) void flash_split(
        const __hip_bfloat16* __restrict__ Q,
        const __hip_bfloat16* __restrict__ K,
        const __hip_bfloat16* __restrict__ Vt,
        const float* __restrict__ mask,
        __hip_bfloat16* __restrict__ Op0, __hip_bfloat16* __restrict__ Op1,
        float* __restrict__ lp0, float* __restrict__ lp1) {
    int bh = blockIdx.y;
    int b = bh >> 4;
    int q0 = blockIdx.x * 64;
    int z  = blockIdx.z;
    __hip_bfloat16* Op = z ? Op1 : Op0;
    float*          lp = z ? lp1 : lp0;
    int tid = threadIdx.x;
    int wave = tid >> 6, lane = tid & 63, quad = lane >> 4, l16 = lane & 15;

    const float SC  = 0.125f * 1.44269504f;
    const float PEN = 1000000.0f * 1.44269504f;

    // Q B-fragments: n=query=l16, k=quad*8+j
    const __hip_bfloat16* Qrow = Q + ((size_t)bh * SS + q0 + wave * 16 + l16) * DH;
    bf16x8 bq0 = *(const bf16x8*)(Qrow + quad * 8);
    bf16x8 bq1 = *(const bf16x8*)(Qrow + 32 + quad * 8);

    const __hip_bfloat16* Kbase = K + (size_t)bh * SS * DH;
    const __hip_bfloat16* Vbase = Vt + (size_t)bh * DH * SS;
    const float* mbase = mask + b * SS;

    const s16x4 aones = (s16x4){0x3F80, 0x3F80, 0x3F80, 0x3F80};  // bf16 1.0 x4

    f32x4 O[4];   // O^T tiles: d = nb2*16 + quad*4 + r, q = l16
#pragma unroll
    for (int i = 0; i < 4; ++i) O[i] = (f32x4){0.f, 0.f, 0.f, 0.f};
    f32x4 lacc = (f32x4){0.f, 0.f, 0.f, 0.f};

    const int kbeg = z * (SS / 2), kend = kbeg + SS / 2;
    for (int k0 = kbeg; k0 < kend; k0 += 128) {
#pragma unroll
        for (int nb = 0; nb < 8; ++nb) {
            int kk = k0 + nb * 16;
            // K A-fragment: m=key=l16, k=quad*8+j (contiguous 16B)
            const __hip_bfloat16* Kr = Kbase + (size_t)(kk + l16) * DH + quad * 8;
            bf16x8 ak0 = *(const bf16x8*)(Kr);
            bf16x8 ak1 = *(const bf16x8*)(Kr + 32);
            f32x4 s = (f32x4){0.f, 0.f, 0.f, 0.f};
            s = __builtin_amdgcn_mfma_f32_16x16x32_bf16(ak0, bq0, s, 0, 0, 0);
            s = __builtin_amdgcn_mfma_f32_16x16x32_bf16(ak1, bq1, s, 0, 0, 0);
            // mask penalty per key row (quad*4+r): one float4 load
            float4 mv = *(const float4*)&mbase[kk + quad * 4];
            float e0 = exp2f(s[0] * SC - PEN * (1.0f - mv.x));
            float e1 = exp2f(s[1] * SC - PEN * (1.0f - mv.y));
            float e2 = exp2f(s[2] * SC - PEN * (1.0f - mv.z));
            float e3 = exp2f(s[3] * SC - PEN * (1.0f - mv.w));
            // pack P^T B-fragment: {e0,e1,e2,e3} as bf16 (k=quad*4+j, n=l16)
            unsigned int p01 = (unsigned int)f2bf(e0) | ((unsigned int)f2bf(e1) << 16);
            unsigned int p23 = (unsigned int)f2bf(e2) | ((unsigned int)f2bf(e3) << 16);
            uint2 pu = {p01, p23};
            s16x4 pb = __builtin_bit_cast(s16x4, pu);
            // row sums: lacc[*][q] += sum_k P^T[k][q]
            lacc = __builtin_amdgcn_mfma_f32_16x16x16bf16_1k(aones, pb, lacc, 0, 0, 0);
            // O^T += Vt-frag x P^T : A[m=d16+l16][k=quad*4+j] contiguous 8B
#pragma unroll
            for (int nb2 = 0; nb2 < 4; ++nb2) {
                const __hip_bfloat16* Vr =
                    Vbase + (size_t)(nb2 * 16 + l16) * SS + kk + quad * 4;
                s16x4 av = *(const s16x4*)(Vr);
                O[nb2] = __builtin_amdgcn_mfma_f32_16x16x16bf16_1k(av, pb, O[nb2], 0, 0, 0);
            }
        }
    }
    // epilogue: Op[bh][d][q] bf16, d = nb2*16 + quad*4 + r, q = q0 + wave*16 + l16
    int qidx = q0 + wave * 16 + l16;
#pragma unroll
    for (int nb2 = 0; nb2 < 4; ++nb2)
#pragma unroll
        for (int r = 0; r < 4; ++r) {
            size_t idx = ((size_t)bh * DH + nb2 * 16 + quad * 4 + r) * SS + qidx;
            ((unsigned short*)Op)[idx] = f2bf(O[nb2][r]);
        }
    if (quad == 0)
        lp[(size_t)bh * SS + qidx] = lacc[0];
}

// -------- combine: ctx[b][q][h*64+d] = (O1+O2)/(l1+l2), transpose via LDS --------
__global__ __launch_bounds__(256) void combine_t(
        const __hip_bfloat16* __restrict__ O1, const __hip_bfloat16* __restrict__ O2,
        const float* __restrict__ l1, const float* __restrict__ l2,
        __hip_bfloat16* __restrict__ chi, __hip_bfloat16* __restrict__ clo) {
    int q0 = blockIdx.x * 64;
    int bh = blockIdx.y;
    int b = bh >> 4, h = bh & 15;
    __shared__ float linv[64];
    __shared__ float tile[64][65];
    int t = threadIdx.x;
    if (t < 64) {
        size_t idx = (size_t)bh * SS + q0 + t;
        linv[t] = 1.0f / (l1[idx] + l2[idx]);
    }
    __syncthreads();
    {
        int d = t >> 2, qo = (t & 3) * 16;
        size_t base = ((size_t)bh * DH + d) * SS + q0 + qo;
        bf16x8 a0 = *(const bf16x8*)(O1 + base);
        bf16x8 a1 = *(const bf16x8*)(O1 + base + 8);
        bf16x8 c0 = *(const bf16x8*)(O2 + base);
        bf16x8 c1 = *(const bf16x8*)(O2 + base + 8);
#pragma unroll
        for (int j = 0; j < 8; ++j)
            tile[qo + j][d] = ((float)a0[j] + (float)c0[j]) * linv[qo + j];
#pragma unroll
        for (int j = 0; j < 8; ++j)
            tile[qo + 8 + j][d] = ((float)a1[j] + (float)c1[j]) * linv[qo + 8 + j];
    }
    __syncthreads();
    {
        int q = t >> 2, dc = (t & 3) * 16;
        bf16x8 hi0, hi1, lo0, lo1;
#pragma unroll
        for (int j = 0; j < 8; ++j) {
            float v = tile[q][dc + j];
            __bf16 hv = (__bf16)v;
            hi0[j] = hv; lo0[j] = (__bf16)(v - (float)hv);
        }
#pragma unroll
        for (int j = 0; j < 8; ++j) {
            float v = tile[q][dc + 8 + j];
            __bf16 hv = (__bf16)v;
            hi1[j] = hv; lo1[j] = (__bf16)(v - (float)hv);
        }
        size_t orow = ((size_t)b * SS + q0 + q) * (NH * DH) + h * DH + dc;
        *(bf16x8*)(chi + orow)     = hi0;
        *(bf16x8*)(chi + orow + 8) = hi1;
        *(bf16x8*)(clo + orow)     = lo0;
        *(bf16x8*)(clo + orow + 8) = lo1;
    }
}

extern "C" void kernel_launch(void* const* d_in, const int* in_sizes, int n_in,
                              void* d_out, int out_size, void* d_ws, size_t ws_size,
                              hipStream_t stream) {
    const float* X    = (const float*)d_in[0];
    const float* mask = (const float*)d_in[1];
    const float* Wq   = (const float*)d_in[2];
    const float* bq   = (const float*)d_in[3];
    const float* Wk   = (const float*)d_in[4];
    const float* bk   = (const float*)d_in[5];
    const float* Wv   = (const float*)d_in[6];
    const float* bv   = (const float*)d_in[7];
    const float* Wo   = (const float*)d_in[8];
    const float* bo   = (const float*)d_in[9];
    float* out = (float*)d_out;

    const size_t MB = 1u << 20;
    char* ws = (char*)d_ws;
    __hip_bfloat16* Xhi   = (__hip_bfloat16*)(ws);            // 0-8 (later ctx_hi)
    __hip_bfloat16* Xlo   = (__hip_bfloat16*)(ws + 8 * MB);   // 8-16 (later ctx_lo)
    __hip_bfloat16* Wt3hi = (__hip_bfloat16*)(ws + 16 * MB);  // 16-22
    __hip_bfloat16* Wt3lo = (__hip_bfloat16*)(ws + 22 * MB);  // 22-28
    __hip_bfloat16* Wothi = (__hip_bfloat16*)(ws + 28 * MB);  // 28-30
    __hip_bfloat16* Wotlo = (__hip_bfloat16*)(ws + 30 * MB);  // 30-32
    __hip_bfloat16* Qw    = (__hip_bfloat16*)(ws + 32 * MB);  // 32-40
    __hip_bfloat16* Kw    = (__hip_bfloat16*)(ws + 40 * MB);  // 40-48
    __hip_bfloat16* Vt    = (__hip_bfloat16*)(ws + 48 * MB);  // 48-56
    // partials alias dead QKV-weight region (only read before flash):
    __hip_bfloat16* Op0   = (__hip_bfloat16*)(ws + 16 * MB);  // 16-24  [B,H,DH,S]
    float*          lp0   = (float*)(ws + 24 * MB);           // 24-24.25
    float*          lp1   = (float*)(ws + 25 * MB);           // 25-25.25
    __hip_bfloat16* Op1   = (__hip_bfloat16*)(ws + 56 * MB);  // 56-64

    split_f32<<<4096, 256, 0, stream>>>((const float4*)X, (ushort4*)Xhi, (ushort4*)Xlo);

    dim3 tgrd(32, 32, 4);
    trans_split4<<<tgrd, 256, 0, stream>>>(Wq, Wk, Wv, Wo, Wt3hi, Wt3lo, Wothi, Wotlo);

    dim3 qkvgrd(3 * DIM / BN, (BB * SS) / BM);   // (48, 32)
    gemm3term<<<qkvgrd, 256, 0, stream>>>(Xhi, Xlo, Wt3hi, Wt3lo, bq, bk, bv,
                                          Qw, Kw, Vt, nullptr, 1);

    dim3 agrd(SS / 64, BB * NH, 2);              // 2048 blocks
    flash_split<<<agrd, 256, 0, stream>>>(Qw, Kw, Vt, mask, Op0, Op1, lp0, lp1);

    dim3 cgrd(SS / 64, BB * NH);                 // 1024 blocks
    combine_t<<<cgrd, 256, 0, stream>>>(Op0, Op1, lp0, lp1, Xhi, Xlo);

    dim3 ogrd(DIM / BN, (BB * SS) / BM);         // (16, 32)
    gemm3term<<<ogrd, 256, 0, stream>>>(Xhi, Xlo, Wothi, Wotlo, bo, nullptr, nullptr,
                                        nullptr, nullptr, nullptr, out, 0);
}

// Round 7
// 333.787 us; speedup vs baseline: 1.7463x; 1.7463x over previous
//
#include <hip/hip_runtime.h>
#include <hip/hip_bf16.h>
#include <math.h>

#define BB 2
#define SS 2048
#define DIM 1024
#define NH 16
#define DH 64

typedef __bf16 bf16x8 __attribute__((ext_vector_type(8)));
typedef float f32x4 __attribute__((ext_vector_type(4)));

__device__ __forceinline__ void glds16(const __hip_bfloat16* g, __hip_bfloat16* l) {
    __builtin_amdgcn_global_load_lds(
        (const __attribute__((address_space(1))) void*)g,
        (__attribute__((address_space(3))) void*)l, 16, 0, 0);
}

// fast fp32 -> bf16 (round-half-up, finite inputs)
__device__ __forceinline__ unsigned short f2bf(float x) {
    unsigned int u = __builtin_bit_cast(unsigned int, x);
    return (unsigned short)((u + 0x8000u) >> 16);
}

// ---------------- prep: split fp32 -> bf16 hi + lo ----------------
__global__ void split_f32(const float4* __restrict__ in,
                          ushort4* __restrict__ hi, ushort4* __restrict__ lo) {
    int i = blockIdx.x * 256 + threadIdx.x;
    float4 v = in[i];
    ushort4 h, l;
    __hip_bfloat16 t;
    t = __float2bfloat16(v.x); h.x = *(ushort*)&t; t = __float2bfloat16(v.x - __bfloat162float(t)); l.x = *(ushort*)&t;
    t = __float2bfloat16(v.y); h.y = *(ushort*)&t; t = __float2bfloat16(v.y - __bfloat162float(t)); l.y = *(ushort*)&t;
    t = __float2bfloat16(v.z); h.z = *(ushort*)&t; t = __float2bfloat16(v.z - __bfloat162float(t)); l.z = *(ushort*)&t;
    t = __float2bfloat16(v.w); h.w = *(ushort*)&t; t = __float2bfloat16(v.w - __bfloat162float(t)); l.w = *(ushort*)&t;
    hi[i] = h; lo[i] = l;
}

// ------- prep: transpose all 4 W [K,N] -> [N,K], split hi/lo (one launch) -------
__global__ void trans_split4(const float* __restrict__ Wq, const float* __restrict__ Wk,
                             const float* __restrict__ Wv, const float* __restrict__ Wo,
                             __hip_bfloat16* __restrict__ T3hi, __hip_bfloat16* __restrict__ T3lo,
                             __hip_bfloat16* __restrict__ Tohi, __hip_bfloat16* __restrict__ Tolo) {
    int z = blockIdx.z;
    const float* W = (z == 0) ? Wq : (z == 1) ? Wk : (z == 2) ? Wv : Wo;
    __hip_bfloat16* Thi = (z < 3) ? T3hi + (size_t)z * DIM * DIM : Tohi;
    __hip_bfloat16* Tlo = (z < 3) ? T3lo + (size_t)z * DIM * DIM : Tolo;
    __shared__ float tile[32][33];
    int k0 = blockIdx.x * 32, n0 = blockIdx.y * 32;
    int t = threadIdx.x;
    int r = t >> 3, c = (t & 7) << 2;
    float4 v = *(const float4*)&W[(size_t)(k0 + r) * DIM + n0 + c];
    tile[r][c] = v.x; tile[r][c + 1] = v.y; tile[r][c + 2] = v.z; tile[r][c + 3] = v.w;
    __syncthreads();
    size_t base = (size_t)(n0 + r) * DIM + k0 + c;
#pragma unroll
    for (int i = 0; i < 4; ++i) {
        float x = tile[c + i][r];
        __hip_bfloat16 h = __float2bfloat16(x);
        Thi[base + i] = h;
        Tlo[base + i] = __float2bfloat16(x - __bfloat162float(h));
    }
}

// ---------------- split-bf16 3-term MFMA GEMM (unchanged, proven) ----------------
#define BM 128
#define BN 64
#define BK 32
__global__ __launch_bounds__(256) void gemm3term(
    const __hip_bfloat16* __restrict__ Ahi, const __hip_bfloat16* __restrict__ Alo,
    const __hip_bfloat16* __restrict__ Bhi, const __hip_bfloat16* __restrict__ Blo,
    const float* __restrict__ b0, const float* __restrict__ b1, const float* __restrict__ b2,
    __hip_bfloat16* __restrict__ oq, __hip_bfloat16* __restrict__ ok,
    __hip_bfloat16* __restrict__ ov, float* __restrict__ of32, int mode) {
    __shared__ alignas(16) __hip_bfloat16 sAh[BM * BK];
    __shared__ alignas(16) __hip_bfloat16 sAl[BM * BK];
    __shared__ alignas(16) __hip_bfloat16 sBh[BN * BK];
    __shared__ alignas(16) __hip_bfloat16 sBl[BN * BK];
    const int K = 1024;
    int tid = threadIdx.x;
    int wave = tid >> 6, lane = tid & 63, quad = lane >> 4, l16 = lane & 15;
    int m0 = blockIdx.y * BM, n0 = blockIdx.x * BN;
    int mo = (wave >> 1) * 64, no = (wave & 1) * 32;

    f32x4 acc[4][2];
#pragma unroll
    for (int i = 0; i < 4; ++i)
#pragma unroll
        for (int j = 0; j < 2; ++j) acc[i][j] = (f32x4){0.f, 0.f, 0.f, 0.f};

    int ar = tid >> 2;
    int ac = (tid & 3) << 3;
    const __hip_bfloat16* gAh = Ahi + (size_t)(m0 + ar) * K + ac;
    const __hip_bfloat16* gAl = Alo + (size_t)(m0 + ar) * K + ac;
    const __hip_bfloat16* gBh = Bhi + (size_t)(n0 + ar) * K + ac;
    const __hip_bfloat16* gBl = Blo + (size_t)(n0 + ar) * K + ac;
    __hip_bfloat16* lAh0 = &sAh[ar * BK + ac];
    __hip_bfloat16* lAh1 = &sAh[(ar + 64) * BK + ac];
    __hip_bfloat16* lAl0 = &sAl[ar * BK + ac];
    __hip_bfloat16* lAl1 = &sAl[(ar + 64) * BK + ac];
    __hip_bfloat16* lBh  = &sBh[ar * BK + ac];
    __hip_bfloat16* lBl  = &sBl[ar * BK + ac];

    for (int k0 = 0; k0 < K; k0 += BK) {
        __syncthreads();
        glds16(gAh + k0, lAh0);
        glds16(gAh + (size_t)64 * K + k0, lAh1);
        glds16(gAl + k0, lAl0);
        glds16(gAl + (size_t)64 * K + k0, lAl1);
        glds16(gBh + k0, lBh);
        glds16(gBl + k0, lBl);
        __syncthreads();

        bf16x8 a_h[4], a_l[4], b_h[2], b_l[2];
#pragma unroll
        for (int i = 0; i < 4; ++i) {
            int off = (mo + i * 16 + l16) * BK + quad * 8;
            a_h[i] = *(const bf16x8*)&sAh[off];
            a_l[i] = *(const bf16x8*)&sAl[off];
        }
#pragma unroll
        for (int j = 0; j < 2; ++j) {
            int off = (no + j * 16 + l16) * BK + quad * 8;
            b_h[j] = *(const bf16x8*)&sBh[off];
            b_l[j] = *(const bf16x8*)&sBl[off];
        }
#pragma unroll
        for (int i = 0; i < 4; ++i)
#pragma unroll
            for (int j = 0; j < 2; ++j) {
                acc[i][j] = __builtin_amdgcn_mfma_f32_16x16x32_bf16(a_h[i], b_h[j], acc[i][j], 0, 0, 0);
                acc[i][j] = __builtin_amdgcn_mfma_f32_16x16x32_bf16(a_h[i], b_l[j], acc[i][j], 0, 0, 0);
                acc[i][j] = __builtin_amdgcn_mfma_f32_16x16x32_bf16(a_l[i], b_h[j], acc[i][j], 0, 0, 0);
            }
    }

    int which = (mode == 1) ? (n0 >> 10) : 0;
    const float* bp = (mode == 0) ? b0 : (which == 0) ? b0 : (which == 1) ? b1 : b2;
#pragma unroll
    for (int i = 0; i < 4; ++i)
#pragma unroll
        for (int j = 0; j < 2; ++j) {
            int gmb = m0 + mo + i * 16 + quad * 4;
            int gn  = n0 + no + j * 16 + l16;
            int nn  = gn & 1023;
            float bb = bp[(mode == 0) ? gn : nn];
#pragma unroll
            for (int r = 0; r < 4; ++r) {
                int gm = gmb + r;
                float v = acc[i][j][r] + bb;
                if (mode == 0) {
                    of32[(size_t)gm * 1024 + gn] = v;
                } else {
                    int b = gm >> 11, s = gm & 2047, h = nn >> 6, d = nn & 63;
                    if (which == 0)
                        oq[(((size_t)(b * NH + h)) * SS + s) * DH + d] = __float2bfloat16(v);
                    else if (which == 1)
                        ok[(((size_t)(b * NH + h)) * SS + s) * DH + d] = __float2bfloat16(v);
                    else
                        ov[(((size_t)(b * NH + h)) * DH + d) * SS + s] = __float2bfloat16(v);
                }
            }
        }
}

// ----- flash v5: GEMM-style LDS staging (glds) shared across waves -----
// r5 compute pipeline (16x16x32, no-max softmax, P via per-wave LDS), but K/V
// tiles staged once per block into LDS half-tiles [rows][32] (the gemm3term
// conflict-free ds_read_b128 pattern).
// Q,K: [B,H,S,DH] bf16.  Vt: [B,H,DH,S] bf16.
// Out: Op [B,S,H*DH] bf16 unnormalized partials, lp [B*H,S] f32 row sums.
#define PSTRIDE 132
__global__ __launch_bounds__(256) void flash_split(
        const __hip_bfloat16* __restrict__ Q,
        const __hip_bfloat16* __restrict__ K,
        const __hip_bfloat16* __restrict__ Vt,
        const float* __restrict__ mask,
        __hip_bfloat16* __restrict__ Op0, __hip_bfloat16* __restrict__ Op1,
        float* __restrict__ lp0, float* __restrict__ lp1) {
    int bh = blockIdx.y;
    int b = bh >> 4, h = bh & (NH - 1);
    int q0 = blockIdx.x * 64;
    int z  = blockIdx.z;
    __hip_bfloat16* Op = z ? Op1 : Op0;
    float*          lp = z ? lp1 : lp0;
    int tid = threadIdx.x;
    int wave = tid >> 6, lane = tid & 63, quad = lane >> 4, l16 = lane & 15;

    // K tile: 128 keys x 64 dh, as two half-tiles [128][32] (dh 0-31, 32-63)
    __shared__ alignas(16) __hip_bfloat16 sK[2][128 * 32];
    // V tile: 64 dh x 128 keys, as four quarter-tiles [64][32] (keys f*32..)
    __shared__ alignas(16) __hip_bfloat16 sV[4][64 * 32];
    __shared__ __hip_bfloat16 Pl[4][16][PSTRIDE];

    const float SC  = 0.125f * 1.44269504f;
    const float PEN = 1000000.0f * 1.44269504f;

    // Q A-fragments (m=query=l16, k=quad*8+j), kept in registers
    const __hip_bfloat16* Qrow = Q + ((size_t)bh * SS + q0 + wave * 16 + l16) * DH;
    bf16x8 aq0 = *(const bf16x8*)(Qrow + quad * 8);
    bf16x8 aq1 = *(const bf16x8*)(Qrow + 32 + quad * 8);

    const __hip_bfloat16* Kbase = K + (size_t)bh * SS * DH;
    const __hip_bfloat16* Vbase = Vt + (size_t)bh * DH * SS;
    const float* mbase = mask + b * SS;

    bf16x8 vones;
#pragma unroll
    for (int j = 0; j < 8; ++j) vones[j] = (__bf16)1.0f;

    f32x4 O[4];
#pragma unroll
    for (int i = 0; i < 4; ++i) O[i] = (f32x4){0.f, 0.f, 0.f, 0.f};
    f32x4 lacc = (f32x4){0.f, 0.f, 0.f, 0.f};

    // staging indices (thread t handles LDS chunk = t within each 4KB issue)
    const int krow = tid >> 2;          // 0..63  (row within 64-row issue)
    const int kq   = (tid & 3) << 3;    // dh/key 16B sub-chunk: 0,8,16,24

    const int kbeg = z * (SS / 2), kend = kbeg + SS / 2;
    for (int k0 = kbeg; k0 < kend; k0 += 128) {
        __syncthreads();   // previous iteration's LDS reads done
        // ---- stage K: 2 halves x 2 issues (64 rows each)
#pragma unroll
        for (int hh = 0; hh < 2; ++hh)
#pragma unroll
            for (int i = 0; i < 2; ++i) {
                int row = i * 64 + krow;
                glds16(Kbase + (size_t)(k0 + row) * DH + hh * 32 + kq,
                       &sK[hh][(size_t)row * 32 + kq]);
            }
        // ---- stage V: 4 quarter-tiles (64 dh rows x 32 keys)
#pragma unroll
        for (int f = 0; f < 4; ++f)
            glds16(Vbase + (size_t)krow * SS + k0 + f * 32 + kq,
                   &sV[f][(size_t)krow * 32 + kq]);
        __syncthreads();   // staging complete

        // ---- S = Q K^T (C: row=query=quad*4+r, col=key=l16 per 16-key block)
#pragma unroll
        for (int nb = 0; nb < 8; ++nb) {
            int roff = (nb * 16 + l16) * 32 + quad * 8;
            bf16x8 bk0 = *(const bf16x8*)&sK[0][roff];
            bf16x8 bk1 = *(const bf16x8*)&sK[1][roff];
            f32x4 s = (f32x4){0.f, 0.f, 0.f, 0.f};
            s = __builtin_amdgcn_mfma_f32_16x16x32_bf16(aq0, bk0, s, 0, 0, 0);
            s = __builtin_amdgcn_mfma_f32_16x16x32_bf16(aq1, bk1, s, 0, 0, 0);
            float pen = PEN * (1.0f - mbase[k0 + nb * 16 + l16]);
#pragma unroll
            for (int r = 0; r < 4; ++r) {
                float e = exp2f(s[r] * SC - pen);
                ((unsigned short*)&Pl[wave][quad * 4 + r][nb * 16 + l16])[0] = f2bf(e);
            }
        }
        // ---- consume P: l += P@1, O += P@V (V B-frags from LDS)
#pragma unroll
        for (int f = 0; f < 4; ++f) {
            bf16x8 ap = *(const bf16x8*)(&Pl[wave][l16][f * 32 + quad * 8]);
            lacc = __builtin_amdgcn_mfma_f32_16x16x32_bf16(ap, vones, lacc, 0, 0, 0);
#pragma unroll
            for (int nb2 = 0; nb2 < 4; ++nb2) {
                bf16x8 bv = *(const bf16x8*)&sV[f][(nb2 * 16 + l16) * 32 + quad * 8];
                O[nb2] = __builtin_amdgcn_mfma_f32_16x16x32_bf16(ap, bv, O[nb2], 0, 0, 0);
            }
        }
    }
    // ---- epilogue: unnormalized partials, ctx layout [B,S,H*DH]
#pragma unroll
    for (int nb2 = 0; nb2 < 4; ++nb2)
#pragma unroll
        for (int r = 0; r < 4; ++r) {
            size_t row = (size_t)b * SS + q0 + wave * 16 + quad * 4 + r;
            ((unsigned short*)Op)[row * (NH * DH) + h * DH + nb2 * 16 + l16] =
                f2bf(O[nb2][r]);
        }
    if (l16 == 0) {
#pragma unroll
        for (int r = 0; r < 4; ++r)
            lp[(size_t)bh * SS + q0 + wave * 16 + quad * 4 + r] = lacc[r];
    }
}

// -------- combine: ctx = (O1+O2)/(l1+l2), split hi/lo --------
__global__ __launch_bounds__(256) void combine(
        const __hip_bfloat16* __restrict__ O1, const __hip_bfloat16* __restrict__ O2,
        const float* __restrict__ l1, const float* __restrict__ l2,
        __hip_bfloat16* __restrict__ chi, __hip_bfloat16* __restrict__ clo) {
    int i = blockIdx.x * 256 + threadIdx.x;
    size_t base = (size_t)i * 8;
    int row = i >> 7;
    int h   = (i >> 3) & 15;
    int b = row >> 11, s = row & 2047;
    size_t bhq = ((size_t)(b * NH + h)) * SS + s;
    float linv = 1.0f / (l1[bhq] + l2[bhq]);
    bf16x8 a = *(const bf16x8*)(O1 + base);
    bf16x8 c = *(const bf16x8*)(O2 + base);
    bf16x8 hi, lo;
#pragma unroll
    for (int j = 0; j < 8; ++j) {
        float v = ((float)a[j] + (float)c[j]) * linv;
        __bf16 hv = (__bf16)v;
        hi[j] = hv;
        lo[j] = (__bf16)(v - (float)hv);
    }
    *(bf16x8*)(chi + base) = hi;
    *(bf16x8*)(clo + base) = lo;
}

extern "C" void kernel_launch(void* const* d_in, const int* in_sizes, int n_in,
                              void* d_out, int out_size, void* d_ws, size_t ws_size,
                              hipStream_t stream) {
    const float* X    = (const float*)d_in[0];
    const float* mask = (const float*)d_in[1];
    const float* Wq   = (const float*)d_in[2];
    const float* bq   = (const float*)d_in[3];
    const float* Wk   = (const float*)d_in[4];
    const float* bk   = (const float*)d_in[5];
    const float* Wv   = (const float*)d_in[6];
    const float* bv   = (const float*)d_in[7];
    const float* Wo   = (const float*)d_in[8];
    const float* bo   = (const float*)d_in[9];
    float* out = (float*)d_out;

    const size_t MB = 1u << 20;
    char* ws = (char*)d_ws;
    __hip_bfloat16* Xhi   = (__hip_bfloat16*)(ws);            // 0-8 (later ctx_hi)
    __hip_bfloat16* Xlo   = (__hip_bfloat16*)(ws + 8 * MB);   // 8-16 (later ctx_lo)
    __hip_bfloat16* Wt3hi = (__hip_bfloat16*)(ws + 16 * MB);  // 16-22
    __hip_bfloat16* Wt3lo = (__hip_bfloat16*)(ws + 22 * MB);  // 22-28
    __hip_bfloat16* Wothi = (__hip_bfloat16*)(ws + 28 * MB);  // 28-30
    __hip_bfloat16* Wotlo = (__hip_bfloat16*)(ws + 30 * MB);  // 30-32
    __hip_bfloat16* Qw    = (__hip_bfloat16*)(ws + 32 * MB);  // 32-40
    __hip_bfloat16* Kw    = (__hip_bfloat16*)(ws + 40 * MB);  // 40-48
    __hip_bfloat16* Vt    = (__hip_bfloat16*)(ws + 48 * MB);  // 48-56
    // partials alias dead QKV-weight region (only read before flash):
    __hip_bfloat16* Op0   = (__hip_bfloat16*)(ws + 16 * MB);  // 16-24
    float*          lp0   = (float*)(ws + 24 * MB);           // 24-24.25
    float*          lp1   = (float*)(ws + 25 * MB);           // 25-25.25
    __hip_bfloat16* Op1   = (__hip_bfloat16*)(ws + 56 * MB);  // 56-64

    split_f32<<<4096, 256, 0, stream>>>((const float4*)X, (ushort4*)Xhi, (ushort4*)Xlo);

    dim3 tgrd(32, 32, 4);
    trans_split4<<<tgrd, 256, 0, stream>>>(Wq, Wk, Wv, Wo, Wt3hi, Wt3lo, Wothi, Wotlo);

    dim3 qkvgrd(3 * DIM / BN, (BB * SS) / BM);   // (48, 32)
    gemm3term<<<qkvgrd, 256, 0, stream>>>(Xhi, Xlo, Wt3hi, Wt3lo, bq, bk, bv,
                                          Qw, Kw, Vt, nullptr, 1);

    dim3 agrd(SS / 64, BB * NH, 2);              // 2048 blocks
    flash_split<<<agrd, 256, 0, stream>>>(Qw, Kw, Vt, mask, Op0, Op1, lp0, lp1);

    combine<<<dim3(2048), 256, 0, stream>>>(Op0, Op1, lp0, lp1, Xhi, Xlo);

    dim3 ogrd(DIM / BN, (BB * SS) / BM);         // (16, 32)
    gemm3term<<<ogrd, 256, 0, stream>>>(Xhi, Xlo, Wothi, Wotlo, bo, nullptr, nullptr,
                                        nullptr, nullptr, nullptr, out, 0);
}

// Round 8
// 329.569 us; speedup vs baseline: 1.7687x; 1.0128x over previous
//
#include <hip/hip_runtime.h>
#include <hip/hip_bf16.h>
#include <math.h>

#define BB 2
#define SS 2048
#define DIM 1024
#define NH 16
#define DH 64

typedef __bf16 bf16x8 __attribute__((ext_vector_type(8)));
typedef float f32x4 __attribute__((ext_vector_type(4)));

__device__ __forceinline__ void glds16(const __hip_bfloat16* g, __hip_bfloat16* l) {
    __builtin_amdgcn_global_load_lds(
        (const __attribute__((address_space(1))) void*)g,
        (__attribute__((address_space(3))) void*)l, 16, 0, 0);
}

// fast fp32 -> bf16 (round-half-up, finite inputs)
__device__ __forceinline__ unsigned short f2bf(float x) {
    unsigned int u = __builtin_bit_cast(unsigned int, x);
    return (unsigned short)((u + 0x8000u) >> 16);
}

// ---------------- prep: split fp32 -> bf16 hi + lo ----------------
__global__ void split_f32(const float4* __restrict__ in,
                          ushort4* __restrict__ hi, ushort4* __restrict__ lo) {
    int i = blockIdx.x * 256 + threadIdx.x;
    float4 v = in[i];
    ushort4 h, l;
    __hip_bfloat16 t;
    t = __float2bfloat16(v.x); h.x = *(ushort*)&t; t = __float2bfloat16(v.x - __bfloat162float(t)); l.x = *(ushort*)&t;
    t = __float2bfloat16(v.y); h.y = *(ushort*)&t; t = __float2bfloat16(v.y - __bfloat162float(t)); l.y = *(ushort*)&t;
    t = __float2bfloat16(v.z); h.z = *(ushort*)&t; t = __float2bfloat16(v.z - __bfloat162float(t)); l.z = *(ushort*)&t;
    t = __float2bfloat16(v.w); h.w = *(ushort*)&t; t = __float2bfloat16(v.w - __bfloat162float(t)); l.w = *(ushort*)&t;
    hi[i] = h; lo[i] = l;
}

// ------- prep: transpose all 4 W [K,N] -> [N,K], split hi/lo (one launch) -------
__global__ void trans_split4(const float* __restrict__ Wq, const float* __restrict__ Wk,
                             const float* __restrict__ Wv, const float* __restrict__ Wo,
                             __hip_bfloat16* __restrict__ T3hi, __hip_bfloat16* __restrict__ T3lo,
                             __hip_bfloat16* __restrict__ Tohi, __hip_bfloat16* __restrict__ Tolo) {
    int z = blockIdx.z;
    const float* W = (z == 0) ? Wq : (z == 1) ? Wk : (z == 2) ? Wv : Wo;
    __hip_bfloat16* Thi = (z < 3) ? T3hi + (size_t)z * DIM * DIM : Tohi;
    __hip_bfloat16* Tlo = (z < 3) ? T3lo + (size_t)z * DIM * DIM : Tolo;
    __shared__ float tile[32][33];
    int k0 = blockIdx.x * 32, n0 = blockIdx.y * 32;
    int t = threadIdx.x;
    int r = t >> 3, c = (t & 7) << 2;
    float4 v = *(const float4*)&W[(size_t)(k0 + r) * DIM + n0 + c];
    tile[r][c] = v.x; tile[r][c + 1] = v.y; tile[r][c + 2] = v.z; tile[r][c + 3] = v.w;
    __syncthreads();
    size_t base = (size_t)(n0 + r) * DIM + k0 + c;
#pragma unroll
    for (int i = 0; i < 4; ++i) {
        float x = tile[c + i][r];
        __hip_bfloat16 h = __float2bfloat16(x);
        Thi[base + i] = h;
        Tlo[base + i] = __float2bfloat16(x - __bfloat162float(h));
    }
}

// ------------- split-bf16 3-term MFMA GEMM, 128x128 tile (m103 config) -------------
// mode 0: of32[m*1024+n] = acc + b0[n]
// mode 1: fused QKV, N=3072: n<1024 -> Q split-heads, <2048 -> K split-heads,
//         else V^T [B,H,DH,S]
#define BM 128
#define BN 128
#define BK 32
__global__ __launch_bounds__(256) void gemm3term(
    const __hip_bfloat16* __restrict__ Ahi, const __hip_bfloat16* __restrict__ Alo,
    const __hip_bfloat16* __restrict__ Bhi, const __hip_bfloat16* __restrict__ Blo,
    const float* __restrict__ b0, const float* __restrict__ b1, const float* __restrict__ b2,
    __hip_bfloat16* __restrict__ oq, __hip_bfloat16* __restrict__ ok,
    __hip_bfloat16* __restrict__ ov, float* __restrict__ of32, int mode) {
    __shared__ alignas(16) __hip_bfloat16 sAh[BM * BK];
    __shared__ alignas(16) __hip_bfloat16 sAl[BM * BK];
    __shared__ alignas(16) __hip_bfloat16 sBh[BN * BK];
    __shared__ alignas(16) __hip_bfloat16 sBl[BN * BK];
    const int K = 1024;
    int tid = threadIdx.x;
    int wave = tid >> 6, lane = tid & 63, quad = lane >> 4, l16 = lane & 15;
    int m0 = blockIdx.y * BM, n0 = blockIdx.x * BN;
    int mo = (wave >> 1) * 64, no = (wave & 1) * 64;

    f32x4 acc[4][4];
#pragma unroll
    for (int i = 0; i < 4; ++i)
#pragma unroll
        for (int j = 0; j < 4; ++j) acc[i][j] = (f32x4){0.f, 0.f, 0.f, 0.f};

    int ar = tid >> 2;
    int ac = (tid & 3) << 3;
    const __hip_bfloat16* gAh = Ahi + (size_t)(m0 + ar) * K + ac;
    const __hip_bfloat16* gAl = Alo + (size_t)(m0 + ar) * K + ac;
    const __hip_bfloat16* gBh = Bhi + (size_t)(n0 + ar) * K + ac;
    const __hip_bfloat16* gBl = Blo + (size_t)(n0 + ar) * K + ac;

    for (int k0 = 0; k0 < K; k0 += BK) {
        __syncthreads();
        glds16(gAh + k0, &sAh[ar * BK + ac]);
        glds16(gAh + (size_t)64 * K + k0, &sAh[(ar + 64) * BK + ac]);
        glds16(gAl + k0, &sAl[ar * BK + ac]);
        glds16(gAl + (size_t)64 * K + k0, &sAl[(ar + 64) * BK + ac]);
        glds16(gBh + k0, &sBh[ar * BK + ac]);
        glds16(gBh + (size_t)64 * K + k0, &sBh[(ar + 64) * BK + ac]);
        glds16(gBl + k0, &sBl[ar * BK + ac]);
        glds16(gBl + (size_t)64 * K + k0, &sBl[(ar + 64) * BK + ac]);
        __syncthreads();

        bf16x8 a_h[4], a_l[4], b_h[4], b_l[4];
#pragma unroll
        for (int i = 0; i < 4; ++i) {
            int off = (mo + i * 16 + l16) * BK + quad * 8;
            a_h[i] = *(const bf16x8*)&sAh[off];
            a_l[i] = *(const bf16x8*)&sAl[off];
        }
#pragma unroll
        for (int j = 0; j < 4; ++j) {
            int off = (no + j * 16 + l16) * BK + quad * 8;
            b_h[j] = *(const bf16x8*)&sBh[off];
            b_l[j] = *(const bf16x8*)&sBl[off];
        }
#pragma unroll
        for (int i = 0; i < 4; ++i)
#pragma unroll
            for (int j = 0; j < 4; ++j) {
                acc[i][j] = __builtin_amdgcn_mfma_f32_16x16x32_bf16(a_h[i], b_h[j], acc[i][j], 0, 0, 0);
                acc[i][j] = __builtin_amdgcn_mfma_f32_16x16x32_bf16(a_h[i], b_l[j], acc[i][j], 0, 0, 0);
                acc[i][j] = __builtin_amdgcn_mfma_f32_16x16x32_bf16(a_l[i], b_h[j], acc[i][j], 0, 0, 0);
            }
    }

    int which = (mode == 1) ? (n0 >> 10) : 0;
    const float* bp = (mode == 0) ? b0 : (which == 0) ? b0 : (which == 1) ? b1 : b2;
#pragma unroll
    for (int i = 0; i < 4; ++i)
#pragma unroll
        for (int j = 0; j < 4; ++j) {
            int gmb = m0 + mo + i * 16 + quad * 4;
            int gn  = n0 + no + j * 16 + l16;
            int nn  = gn & 1023;
            float bb = bp[(mode == 0) ? gn : nn];
#pragma unroll
            for (int r = 0; r < 4; ++r) {
                int gm = gmb + r;
                float v = acc[i][j][r] + bb;
                if (mode == 0) {
                    of32[(size_t)gm * 1024 + gn] = v;
                } else {
                    int b = gm >> 11, s = gm & 2047, h = nn >> 6, d = nn & 63;
                    if (which == 0)
                        oq[(((size_t)(b * NH + h)) * SS + s) * DH + d] = __float2bfloat16(v);
                    else if (which == 1)
                        ok[(((size_t)(b * NH + h)) * SS + s) * DH + d] = __float2bfloat16(v);
                    else
                        ov[(((size_t)(b * NH + h)) * DH + d) * SS + s] = __float2bfloat16(v);
                }
            }
        }
}

// ----- flash v6: 128-query tile, 64-key step, shared LDS staging -----
// Each of 4 waves owns 32 queries (two 16-row fragment groups). K/V fragments
// from LDS are reused across both groups (2 MFMA per ds_read).
// Q,K: [B,H,S,DH] bf16.  Vt: [B,H,DH,S] bf16.
// Out: Op [B,S,H*DH] bf16 unnormalized partials, lp [B*H,S] f32 row sums.
#define PSTR 68
__global__ __launch_bounds__(256) void flash_split(
        const __hip_bfloat16* __restrict__ Q,
        const __hip_bfloat16* __restrict__ K,
        const __hip_bfloat16* __restrict__ Vt,
        const float* __restrict__ mask,
        __hip_bfloat16* __restrict__ Op0, __hip_bfloat16* __restrict__ Op1,
        float* __restrict__ lp0, float* __restrict__ lp1) {
    int bh = blockIdx.y;
    int b = bh >> 4, h = bh & (NH - 1);
    int q0 = blockIdx.x * 128;
    int z  = blockIdx.z;
    __hip_bfloat16* Op = z ? Op1 : Op0;
    float*          lp = z ? lp1 : lp0;
    int tid = threadIdx.x;
    int wave = tid >> 6, lane = tid & 63, quad = lane >> 4, l16 = lane & 15;

    // K tile: 64 keys x 64 dh as two half-tiles [64][32] (dh 0-31 / 32-63): 8 KB
    __shared__ alignas(16) __hip_bfloat16 sK[2][64 * 32];
    // V tile: 64 dh x 64 keys as two half-tiles [64][32] (keys c*32..): 8 KB
    __shared__ alignas(16) __hip_bfloat16 sV[2][64 * 32];
    // P staging per wave: 32 q rows x 64 keys (padded): 17.4 KB
    __shared__ __hip_bfloat16 Pl[4][32][PSTR];

    const float SC  = 0.125f * 1.44269504f;
    const float PEN = 1000000.0f * 1.44269504f;

    // Q A-fragments for both 16-row groups
    bf16x8 aq[2][2];
#pragma unroll
    for (int g = 0; g < 2; ++g) {
        const __hip_bfloat16* Qrow =
            Q + ((size_t)bh * SS + q0 + wave * 32 + g * 16 + l16) * DH;
        aq[g][0] = *(const bf16x8*)(Qrow + quad * 8);
        aq[g][1] = *(const bf16x8*)(Qrow + 32 + quad * 8);
    }

    const __hip_bfloat16* Kbase = K + (size_t)bh * SS * DH;
    const __hip_bfloat16* Vbase = Vt + (size_t)bh * DH * SS;
    const float* mbase = mask + b * SS;

    bf16x8 vones;
#pragma unroll
    for (int j = 0; j < 8; ++j) vones[j] = (__bf16)1.0f;

    f32x4 O[2][4];
#pragma unroll
    for (int g = 0; g < 2; ++g)
#pragma unroll
        for (int i = 0; i < 4; ++i) O[g][i] = (f32x4){0.f, 0.f, 0.f, 0.f};
    f32x4 lacc[2] = {(f32x4){0.f, 0.f, 0.f, 0.f}, (f32x4){0.f, 0.f, 0.f, 0.f}};

    const int krow = tid >> 2;          // 0..63
    const int kq   = (tid & 3) << 3;    // 0,8,16,24

    const int kbeg = z * (SS / 2), kend = kbeg + SS / 2;
    for (int k0 = kbeg; k0 < kend; k0 += 64) {
        __syncthreads();
        // stage K (64 keys x 64 dh)
        glds16(Kbase + (size_t)(k0 + krow) * DH + kq,      &sK[0][krow * 32 + kq]);
        glds16(Kbase + (size_t)(k0 + krow) * DH + 32 + kq, &sK[1][krow * 32 + kq]);
        // stage V (64 dh x 64 keys)
        glds16(Vbase + (size_t)krow * SS + k0 + kq,        &sV[0][krow * 32 + kq]);
        glds16(Vbase + (size_t)krow * SS + k0 + 32 + kq,   &sV[1][krow * 32 + kq]);
        __syncthreads();

        // S = Q K^T for 4 nb (16-key blocks), both q-groups share bk frags
#pragma unroll
        for (int nb = 0; nb < 4; ++nb) {
            int roff = (nb * 16 + l16) * 32 + quad * 8;
            bf16x8 bk0 = *(const bf16x8*)&sK[0][roff];
            bf16x8 bk1 = *(const bf16x8*)&sK[1][roff];
            float pen = PEN * (1.0f - mbase[k0 + nb * 16 + l16]);
#pragma unroll
            for (int g = 0; g < 2; ++g) {
                f32x4 s = (f32x4){0.f, 0.f, 0.f, 0.f};
                s = __builtin_amdgcn_mfma_f32_16x16x32_bf16(aq[g][0], bk0, s, 0, 0, 0);
                s = __builtin_amdgcn_mfma_f32_16x16x32_bf16(aq[g][1], bk1, s, 0, 0, 0);
#pragma unroll
                for (int r = 0; r < 4; ++r) {
                    float e = exp2f(s[r] * SC - pen);
                    ((unsigned short*)&Pl[wave][g * 16 + quad * 4 + r][nb * 16 + l16])[0] = f2bf(e);
                }
            }
        }
        // consume P: l += P@1, O += P@V (bv frags shared across q-groups)
#pragma unroll
        for (int c = 0; c < 2; ++c) {
            bf16x8 ap0 = *(const bf16x8*)(&Pl[wave][l16][c * 32 + quad * 8]);
            bf16x8 ap1 = *(const bf16x8*)(&Pl[wave][16 + l16][c * 32 + quad * 8]);
            lacc[0] = __builtin_amdgcn_mfma_f32_16x16x32_bf16(ap0, vones, lacc[0], 0, 0, 0);
            lacc[1] = __builtin_amdgcn_mfma_f32_16x16x32_bf16(ap1, vones, lacc[1], 0, 0, 0);
#pragma unroll
            for (int nb2 = 0; nb2 < 4; ++nb2) {
                bf16x8 bv = *(const bf16x8*)&sV[c][(nb2 * 16 + l16) * 32 + quad * 8];
                O[0][nb2] = __builtin_amdgcn_mfma_f32_16x16x32_bf16(ap0, bv, O[0][nb2], 0, 0, 0);
                O[1][nb2] = __builtin_amdgcn_mfma_f32_16x16x32_bf16(ap1, bv, O[1][nb2], 0, 0, 0);
            }
        }
    }
    // epilogue: unnormalized partials, ctx layout [B,S,H*DH]
#pragma unroll
    for (int g = 0; g < 2; ++g) {
#pragma unroll
        for (int nb2 = 0; nb2 < 4; ++nb2)
#pragma unroll
            for (int r = 0; r < 4; ++r) {
                size_t row = (size_t)b * SS + q0 + wave * 32 + g * 16 + quad * 4 + r;
                ((unsigned short*)Op)[row * (NH * DH) + h * DH + nb2 * 16 + l16] =
                    f2bf(O[g][nb2][r]);
            }
        if (l16 == 0) {
#pragma unroll
            for (int r = 0; r < 4; ++r)
                lp[(size_t)bh * SS + q0 + wave * 32 + g * 16 + quad * 4 + r] = lacc[g][r];
        }
    }
}

// -------- combine: ctx = (O1+O2)/(l1+l2), split hi/lo --------
__global__ __launch_bounds__(256) void combine(
        const __hip_bfloat16* __restrict__ O1, const __hip_bfloat16* __restrict__ O2,
        const float* __restrict__ l1, const float* __restrict__ l2,
        __hip_bfloat16* __restrict__ chi, __hip_bfloat16* __restrict__ clo) {
    int i = blockIdx.x * 256 + threadIdx.x;
    size_t base = (size_t)i * 8;
    int row = i >> 7;
    int h   = (i >> 3) & 15;
    int b = row >> 11, s = row & 2047;
    size_t bhq = ((size_t)(b * NH + h)) * SS + s;
    float linv = 1.0f / (l1[bhq] + l2[bhq]);
    bf16x8 a = *(const bf16x8*)(O1 + base);
    bf16x8 c = *(const bf16x8*)(O2 + base);
    bf16x8 hi, lo;
#pragma unroll
    for (int j = 0; j < 8; ++j) {
        float v = ((float)a[j] + (float)c[j]) * linv;
        __bf16 hv = (__bf16)v;
        hi[j] = hv;
        lo[j] = (__bf16)(v - (float)hv);
    }
    *(bf16x8*)(chi + base) = hi;
    *(bf16x8*)(clo + base) = lo;
}

extern "C" void kernel_launch(void* const* d_in, const int* in_sizes, int n_in,
                              void* d_out, int out_size, void* d_ws, size_t ws_size,
                              hipStream_t stream) {
    const float* X    = (const float*)d_in[0];
    const float* mask = (const float*)d_in[1];
    const float* Wq   = (const float*)d_in[2];
    const float* bq   = (const float*)d_in[3];
    const float* Wk   = (const float*)d_in[4];
    const float* bk   = (const float*)d_in[5];
    const float* Wv   = (const float*)d_in[6];
    const float* bv   = (const float*)d_in[7];
    const float* Wo   = (const float*)d_in[8];
    const float* bo   = (const float*)d_in[9];
    float* out = (float*)d_out;

    const size_t MB = 1u << 20;
    char* ws = (char*)d_ws;
    __hip_bfloat16* Xhi   = (__hip_bfloat16*)(ws);            // 0-8 (later ctx_hi)
    __hip_bfloat16* Xlo   = (__hip_bfloat16*)(ws + 8 * MB);   // 8-16 (later ctx_lo)
    __hip_bfloat16* Wt3hi = (__hip_bfloat16*)(ws + 16 * MB);  // 16-22
    __hip_bfloat16* Wt3lo = (__hip_bfloat16*)(ws + 22 * MB);  // 22-28
    __hip_bfloat16* Wothi = (__hip_bfloat16*)(ws + 28 * MB);  // 28-30
    __hip_bfloat16* Wotlo = (__hip_bfloat16*)(ws + 30 * MB);  // 30-32
    __hip_bfloat16* Qw    = (__hip_bfloat16*)(ws + 32 * MB);  // 32-40
    __hip_bfloat16* Kw    = (__hip_bfloat16*)(ws + 40 * MB);  // 40-48
    __hip_bfloat16* Vt    = (__hip_bfloat16*)(ws + 48 * MB);  // 48-56
    // partials alias dead QKV-weight region (only read before flash):
    __hip_bfloat16* Op0   = (__hip_bfloat16*)(ws + 16 * MB);  // 16-24
    float*          lp0   = (float*)(ws + 24 * MB);           // 24-24.25
    float*          lp1   = (float*)(ws + 25 * MB);           // 25-25.25
    __hip_bfloat16* Op1   = (__hip_bfloat16*)(ws + 56 * MB);  // 56-64

    split_f32<<<4096, 256, 0, stream>>>((const float4*)X, (ushort4*)Xhi, (ushort4*)Xlo);

    dim3 tgrd(32, 32, 4);
    trans_split4<<<tgrd, 256, 0, stream>>>(Wq, Wk, Wv, Wo, Wt3hi, Wt3lo, Wothi, Wotlo);

    dim3 qkvgrd(3 * DIM / BN, (BB * SS) / BM);   // (24, 32)
    gemm3term<<<qkvgrd, 256, 0, stream>>>(Xhi, Xlo, Wt3hi, Wt3lo, bq, bk, bv,
                                          Qw, Kw, Vt, nullptr, 1);

    dim3 agrd(SS / 128, BB * NH, 2);             // (16, 32, 2) = 1024 blocks
    flash_split<<<agrd, 256, 0, stream>>>(Qw, Kw, Vt, mask, Op0, Op1, lp0, lp1);

    combine<<<dim3(2048), 256, 0, stream>>>(Op0, Op1, lp0, lp1, Xhi, Xlo);

    dim3 ogrd(DIM / BN, (BB * SS) / BM);         // (8, 32)
    gemm3term<<<ogrd, 256, 0, stream>>>(Xhi, Xlo, Wothi, Wotlo, bo, nullptr, nullptr,
                                        nullptr, nullptr, nullptr, out, 0);
}

// Round 9
// 282.646 us; speedup vs baseline: 2.0623x; 1.1660x over previous
//
#include <hip/hip_runtime.h>
#include <hip/hip_bf16.h>
#include <math.h>

#define BB 2
#define SS 2048
#define DIM 1024
#define NH 16
#define DH 64

typedef __bf16 bf16x8 __attribute__((ext_vector_type(8)));
typedef float f32x4 __attribute__((ext_vector_type(4)));

__device__ __forceinline__ void glds16(const __hip_bfloat16* g, __hip_bfloat16* l) {
    __builtin_amdgcn_global_load_lds(
        (const __attribute__((address_space(1))) void*)g,
        (__attribute__((address_space(3))) void*)l, 16, 0, 0);
}

// fast fp32 -> bf16 (round-half-up, finite inputs)
__device__ __forceinline__ unsigned short f2bf(float x) {
    unsigned int u = __builtin_bit_cast(unsigned int, x);
    return (unsigned short)((u + 0x8000u) >> 16);
}

// ---------------- prep: split fp32 -> bf16 hi + lo ----------------
__global__ void split_f32(const float4* __restrict__ in,
                          ushort4* __restrict__ hi, ushort4* __restrict__ lo) {
    int i = blockIdx.x * 256 + threadIdx.x;
    float4 v = in[i];
    ushort4 h, l;
    __hip_bfloat16 t;
    t = __float2bfloat16(v.x); h.x = *(ushort*)&t; t = __float2bfloat16(v.x - __bfloat162float(t)); l.x = *(ushort*)&t;
    t = __float2bfloat16(v.y); h.y = *(ushort*)&t; t = __float2bfloat16(v.y - __bfloat162float(t)); l.y = *(ushort*)&t;
    t = __float2bfloat16(v.z); h.z = *(ushort*)&t; t = __float2bfloat16(v.z - __bfloat162float(t)); l.z = *(ushort*)&t;
    t = __float2bfloat16(v.w); h.w = *(ushort*)&t; t = __float2bfloat16(v.w - __bfloat162float(t)); l.w = *(ushort*)&t;
    hi[i] = h; lo[i] = l;
}

// ------- prep: transpose all 4 W [K,N] -> [N,K], split hi/lo (one launch) -------
__global__ void trans_split4(const float* __restrict__ Wq, const float* __restrict__ Wk,
                             const float* __restrict__ Wv, const float* __restrict__ Wo,
                             __hip_bfloat16* __restrict__ T3hi, __hip_bfloat16* __restrict__ T3lo,
                             __hip_bfloat16* __restrict__ Tohi, __hip_bfloat16* __restrict__ Tolo) {
    int z = blockIdx.z;
    const float* W = (z == 0) ? Wq : (z == 1) ? Wk : (z == 2) ? Wv : Wo;
    __hip_bfloat16* Thi = (z < 3) ? T3hi + (size_t)z * DIM * DIM : Tohi;
    __hip_bfloat16* Tlo = (z < 3) ? T3lo + (size_t)z * DIM * DIM : Tolo;
    __shared__ float tile[32][33];
    int k0 = blockIdx.x * 32, n0 = blockIdx.y * 32;
    int t = threadIdx.x;
    int r = t >> 3, c = (t & 7) << 2;
    float4 v = *(const float4*)&W[(size_t)(k0 + r) * DIM + n0 + c];
    tile[r][c] = v.x; tile[r][c + 1] = v.y; tile[r][c + 2] = v.z; tile[r][c + 3] = v.w;
    __syncthreads();
    size_t base = (size_t)(n0 + r) * DIM + k0 + c;
#pragma unroll
    for (int i = 0; i < 4; ++i) {
        float x = tile[c + i][r];
        __hip_bfloat16 h = __float2bfloat16(x);
        Thi[base + i] = h;
        Tlo[base + i] = __float2bfloat16(x - __bfloat162float(h));
    }
}

// ------------- bf16 MFMA GEMM, 128x128 tile, NT=1 (plain) or NT=3 (split) -------------
// mode 0: of32[m*1024+n] = acc + b0[n]
// mode 1: fused QKV, N=3072: n<1024 -> Q split-heads, <2048 -> K split-heads,
//         else V^T [B,H,DH,S]
#define BM 128
#define BN 128
#define BK 32
template<int NT>
__global__ __launch_bounds__(256) void gemm_t(
    const __hip_bfloat16* __restrict__ Ahi, const __hip_bfloat16* __restrict__ Alo,
    const __hip_bfloat16* __restrict__ Bhi, const __hip_bfloat16* __restrict__ Blo,
    const float* __restrict__ b0, const float* __restrict__ b1, const float* __restrict__ b2,
    __hip_bfloat16* __restrict__ oq, __hip_bfloat16* __restrict__ ok,
    __hip_bfloat16* __restrict__ ov, float* __restrict__ of32, int mode) {
    __shared__ alignas(16) __hip_bfloat16 sAh[BM * BK];
    __shared__ alignas(16) __hip_bfloat16 sBh[BN * BK];
    __shared__ alignas(16) __hip_bfloat16 sAl[NT == 3 ? BM * BK : 16];
    __shared__ alignas(16) __hip_bfloat16 sBl[NT == 3 ? BN * BK : 16];
    const int K = 1024;
    int tid = threadIdx.x;
    int wave = tid >> 6, lane = tid & 63, quad = lane >> 4, l16 = lane & 15;
    int m0 = blockIdx.y * BM, n0 = blockIdx.x * BN;
    int mo = (wave >> 1) * 64, no = (wave & 1) * 64;

    f32x4 acc[4][4];
#pragma unroll
    for (int i = 0; i < 4; ++i)
#pragma unroll
        for (int j = 0; j < 4; ++j) acc[i][j] = (f32x4){0.f, 0.f, 0.f, 0.f};

    int ar = tid >> 2;
    int ac = (tid & 3) << 3;
    const __hip_bfloat16* gAh = Ahi + (size_t)(m0 + ar) * K + ac;
    const __hip_bfloat16* gBh = Bhi + (size_t)(n0 + ar) * K + ac;
    const __hip_bfloat16* gAl = (NT == 3) ? Alo + (size_t)(m0 + ar) * K + ac : nullptr;
    const __hip_bfloat16* gBl = (NT == 3) ? Blo + (size_t)(n0 + ar) * K + ac : nullptr;

    for (int k0 = 0; k0 < K; k0 += BK) {
        __syncthreads();
        glds16(gAh + k0, &sAh[ar * BK + ac]);
        glds16(gAh + (size_t)64 * K + k0, &sAh[(ar + 64) * BK + ac]);
        glds16(gBh + k0, &sBh[ar * BK + ac]);
        glds16(gBh + (size_t)64 * K + k0, &sBh[(ar + 64) * BK + ac]);
        if (NT == 3) {
            glds16(gAl + k0, &sAl[ar * BK + ac]);
            glds16(gAl + (size_t)64 * K + k0, &sAl[(ar + 64) * BK + ac]);
            glds16(gBl + k0, &sBl[ar * BK + ac]);
            glds16(gBl + (size_t)64 * K + k0, &sBl[(ar + 64) * BK + ac]);
        }
        __syncthreads();

        bf16x8 a_h[4], b_h[4];
#pragma unroll
        for (int i = 0; i < 4; ++i)
            a_h[i] = *(const bf16x8*)&sAh[(mo + i * 16 + l16) * BK + quad * 8];
#pragma unroll
        for (int j = 0; j < 4; ++j)
            b_h[j] = *(const bf16x8*)&sBh[(no + j * 16 + l16) * BK + quad * 8];
#pragma unroll
        for (int i = 0; i < 4; ++i)
#pragma unroll
            for (int j = 0; j < 4; ++j)
                acc[i][j] = __builtin_amdgcn_mfma_f32_16x16x32_bf16(a_h[i], b_h[j], acc[i][j], 0, 0, 0);
        if (NT == 3) {
            bf16x8 a_l[4], b_l[4];
#pragma unroll
            for (int i = 0; i < 4; ++i)
                a_l[i] = *(const bf16x8*)&sAl[(mo + i * 16 + l16) * BK + quad * 8];
#pragma unroll
            for (int j = 0; j < 4; ++j)
                b_l[j] = *(const bf16x8*)&sBl[(no + j * 16 + l16) * BK + quad * 8];
#pragma unroll
            for (int i = 0; i < 4; ++i)
#pragma unroll
                for (int j = 0; j < 4; ++j) {
                    acc[i][j] = __builtin_amdgcn_mfma_f32_16x16x32_bf16(a_h[i], b_l[j], acc[i][j], 0, 0, 0);
                    acc[i][j] = __builtin_amdgcn_mfma_f32_16x16x32_bf16(a_l[i], b_h[j], acc[i][j], 0, 0, 0);
                }
        }
    }

    int which = (mode == 1) ? (n0 >> 10) : 0;
    const float* bp = (mode == 0) ? b0 : (which == 0) ? b0 : (which == 1) ? b1 : b2;
#pragma unroll
    for (int i = 0; i < 4; ++i)
#pragma unroll
        for (int j = 0; j < 4; ++j) {
            int gmb = m0 + mo + i * 16 + quad * 4;
            int gn  = n0 + no + j * 16 + l16;
            int nn  = gn & 1023;
            float bb = bp[(mode == 0) ? gn : nn];
#pragma unroll
            for (int r = 0; r < 4; ++r) {
                int gm = gmb + r;
                float v = acc[i][j][r] + bb;
                if (mode == 0) {
                    of32[(size_t)gm * 1024 + gn] = v;
                } else {
                    int b = gm >> 11, s = gm & 2047, h = nn >> 6, d = nn & 63;
                    if (which == 0)
                        oq[(((size_t)(b * NH + h)) * SS + s) * DH + d] = __float2bfloat16(v);
                    else if (which == 1)
                        ok[(((size_t)(b * NH + h)) * SS + s) * DH + d] = __float2bfloat16(v);
                    else
                        ov[(((size_t)(b * NH + h)) * DH + d) * SS + s] = __float2bfloat16(v);
                }
            }
        }
}

// ----- flash v6: 128-query tile, 64-key step, shared LDS staging (unchanged) -----
#define PSTR 68
__global__ __launch_bounds__(256) void flash_split(
        const __hip_bfloat16* __restrict__ Q,
        const __hip_bfloat16* __restrict__ K,
        const __hip_bfloat16* __restrict__ Vt,
        const float* __restrict__ mask,
        __hip_bfloat16* __restrict__ Op0, __hip_bfloat16* __restrict__ Op1,
        float* __restrict__ lp0, float* __restrict__ lp1) {
    int bh = blockIdx.y;
    int b = bh >> 4, h = bh & (NH - 1);
    int q0 = blockIdx.x * 128;
    int z  = blockIdx.z;
    __hip_bfloat16* Op = z ? Op1 : Op0;
    float*          lp = z ? lp1 : lp0;
    int tid = threadIdx.x;
    int wave = tid >> 6, lane = tid & 63, quad = lane >> 4, l16 = lane & 15;

    __shared__ alignas(16) __hip_bfloat16 sK[2][64 * 32];
    __shared__ alignas(16) __hip_bfloat16 sV[2][64 * 32];
    __shared__ __hip_bfloat16 Pl[4][32][PSTR];

    const float SC  = 0.125f * 1.44269504f;
    const float PEN = 1000000.0f * 1.44269504f;

    bf16x8 aq[2][2];
#pragma unroll
    for (int g = 0; g < 2; ++g) {
        const __hip_bfloat16* Qrow =
            Q + ((size_t)bh * SS + q0 + wave * 32 + g * 16 + l16) * DH;
        aq[g][0] = *(const bf16x8*)(Qrow + quad * 8);
        aq[g][1] = *(const bf16x8*)(Qrow + 32 + quad * 8);
    }

    const __hip_bfloat16* Kbase = K + (size_t)bh * SS * DH;
    const __hip_bfloat16* Vbase = Vt + (size_t)bh * DH * SS;
    const float* mbase = mask + b * SS;

    bf16x8 vones;
#pragma unroll
    for (int j = 0; j < 8; ++j) vones[j] = (__bf16)1.0f;

    f32x4 O[2][4];
#pragma unroll
    for (int g = 0; g < 2; ++g)
#pragma unroll
        for (int i = 0; i < 4; ++i) O[g][i] = (f32x4){0.f, 0.f, 0.f, 0.f};
    f32x4 lacc[2] = {(f32x4){0.f, 0.f, 0.f, 0.f}, (f32x4){0.f, 0.f, 0.f, 0.f}};

    const int krow = tid >> 2;
    const int kq   = (tid & 3) << 3;

    const int kbeg = z * (SS / 2), kend = kbeg + SS / 2;
    for (int k0 = kbeg; k0 < kend; k0 += 64) {
        __syncthreads();
        glds16(Kbase + (size_t)(k0 + krow) * DH + kq,      &sK[0][krow * 32 + kq]);
        glds16(Kbase + (size_t)(k0 + krow) * DH + 32 + kq, &sK[1][krow * 32 + kq]);
        glds16(Vbase + (size_t)krow * SS + k0 + kq,        &sV[0][krow * 32 + kq]);
        glds16(Vbase + (size_t)krow * SS + k0 + 32 + kq,   &sV[1][krow * 32 + kq]);
        __syncthreads();

#pragma unroll
        for (int nb = 0; nb < 4; ++nb) {
            int roff = (nb * 16 + l16) * 32 + quad * 8;
            bf16x8 bk0 = *(const bf16x8*)&sK[0][roff];
            bf16x8 bk1 = *(const bf16x8*)&sK[1][roff];
            float pen = PEN * (1.0f - mbase[k0 + nb * 16 + l16]);
#pragma unroll
            for (int g = 0; g < 2; ++g) {
                f32x4 s = (f32x4){0.f, 0.f, 0.f, 0.f};
                s = __builtin_amdgcn_mfma_f32_16x16x32_bf16(aq[g][0], bk0, s, 0, 0, 0);
                s = __builtin_amdgcn_mfma_f32_16x16x32_bf16(aq[g][1], bk1, s, 0, 0, 0);
#pragma unroll
                for (int r = 0; r < 4; ++r) {
                    float e = exp2f(s[r] * SC - pen);
                    ((unsigned short*)&Pl[wave][g * 16 + quad * 4 + r][nb * 16 + l16])[0] = f2bf(e);
                }
            }
        }
#pragma unroll
        for (int c = 0; c < 2; ++c) {
            bf16x8 ap0 = *(const bf16x8*)(&Pl[wave][l16][c * 32 + quad * 8]);
            bf16x8 ap1 = *(const bf16x8*)(&Pl[wave][16 + l16][c * 32 + quad * 8]);
            lacc[0] = __builtin_amdgcn_mfma_f32_16x16x32_bf16(ap0, vones, lacc[0], 0, 0, 0);
            lacc[1] = __builtin_amdgcn_mfma_f32_16x16x32_bf16(ap1, vones, lacc[1], 0, 0, 0);
#pragma unroll
            for (int nb2 = 0; nb2 < 4; ++nb2) {
                bf16x8 bv = *(const bf16x8*)&sV[c][(nb2 * 16 + l16) * 32 + quad * 8];
                O[0][nb2] = __builtin_amdgcn_mfma_f32_16x16x32_bf16(ap0, bv, O[0][nb2], 0, 0, 0);
                O[1][nb2] = __builtin_amdgcn_mfma_f32_16x16x32_bf16(ap1, bv, O[1][nb2], 0, 0, 0);
            }
        }
    }
#pragma unroll
    for (int g = 0; g < 2; ++g) {
#pragma unroll
        for (int nb2 = 0; nb2 < 4; ++nb2)
#pragma unroll
            for (int r = 0; r < 4; ++r) {
                size_t row = (size_t)b * SS + q0 + wave * 32 + g * 16 + quad * 4 + r;
                ((unsigned short*)Op)[row * (NH * DH) + h * DH + nb2 * 16 + l16] =
                    f2bf(O[g][nb2][r]);
            }
        if (l16 == 0) {
#pragma unroll
            for (int r = 0; r < 4; ++r)
                lp[(size_t)bh * SS + q0 + wave * 32 + g * 16 + quad * 4 + r] = lacc[g][r];
        }
    }
}

// -------- combine: ctx = (O1+O2)/(l1+l2), split hi/lo --------
__global__ __launch_bounds__(256) void combine(
        const __hip_bfloat16* __restrict__ O1, const __hip_bfloat16* __restrict__ O2,
        const float* __restrict__ l1, const float* __restrict__ l2,
        __hip_bfloat16* __restrict__ chi, __hip_bfloat16* __restrict__ clo) {
    int i = blockIdx.x * 256 + threadIdx.x;
    size_t base = (size_t)i * 8;
    int row = i >> 7;
    int h   = (i >> 3) & 15;
    int b = row >> 11, s = row & 2047;
    size_t bhq = ((size_t)(b * NH + h)) * SS + s;
    float linv = 1.0f / (l1[bhq] + l2[bhq]);
    bf16x8 a = *(const bf16x8*)(O1 + base);
    bf16x8 c = *(const bf16x8*)(O2 + base);
    bf16x8 hi, lo;
#pragma unroll
    for (int j = 0; j < 8; ++j) {
        float v = ((float)a[j] + (float)c[j]) * linv;
        __bf16 hv = (__bf16)v;
        hi[j] = hv;
        lo[j] = (__bf16)(v - (float)hv);
    }
    *(bf16x8*)(chi + base) = hi;
    *(bf16x8*)(clo + base) = lo;
}

extern "C" void kernel_launch(void* const* d_in, const int* in_sizes, int n_in,
                              void* d_out, int out_size, void* d_ws, size_t ws_size,
                              hipStream_t stream) {
    const float* X    = (const float*)d_in[0];
    const float* mask = (const float*)d_in[1];
    const float* Wq   = (const float*)d_in[2];
    const float* bq   = (const float*)d_in[3];
    const float* Wk   = (const float*)d_in[4];
    const float* bk   = (const float*)d_in[5];
    const float* Wv   = (const float*)d_in[6];
    const float* bv   = (const float*)d_in[7];
    const float* Wo   = (const float*)d_in[8];
    const float* bo   = (const float*)d_in[9];
    float* out = (float*)d_out;

    const size_t MB = 1u << 20;
    char* ws = (char*)d_ws;
    __hip_bfloat16* Xhi   = (__hip_bfloat16*)(ws);            // 0-8 (later ctx_hi)
    __hip_bfloat16* Xlo   = (__hip_bfloat16*)(ws + 8 * MB);   // 8-16 (later ctx_lo)
    __hip_bfloat16* Wt3hi = (__hip_bfloat16*)(ws + 16 * MB);  // 16-22
    __hip_bfloat16* Wt3lo = (__hip_bfloat16*)(ws + 22 * MB);  // 22-28
    __hip_bfloat16* Wothi = (__hip_bfloat16*)(ws + 28 * MB);  // 28-30
    __hip_bfloat16* Wotlo = (__hip_bfloat16*)(ws + 30 * MB);  // 30-32
    __hip_bfloat16* Qw    = (__hip_bfloat16*)(ws + 32 * MB);  // 32-40
    __hip_bfloat16* Kw    = (__hip_bfloat16*)(ws + 40 * MB);  // 40-48
    __hip_bfloat16* Vt    = (__hip_bfloat16*)(ws + 48 * MB);  // 48-56
    // partials alias dead QKV-weight region (only read before flash):
    __hip_bfloat16* Op0   = (__hip_bfloat16*)(ws + 16 * MB);  // 16-24
    float*          lp0   = (float*)(ws + 24 * MB);           // 24-24.25
    float*          lp1   = (float*)(ws + 25 * MB);           // 25-25.25
    __hip_bfloat16* Op1   = (__hip_bfloat16*)(ws + 56 * MB);  // 56-64

    split_f32<<<4096, 256, 0, stream>>>((const float4*)X, (ushort4*)Xhi, (ushort4*)Xlo);

    dim3 tgrd(32, 32, 4);
    trans_split4<<<tgrd, 256, 0, stream>>>(Wq, Wk, Wv, Wo, Wt3hi, Wt3lo, Wothi, Wotlo);

    // QKV: plain bf16 (1-term) — Q/K/V are bf16-rounded immediately anyway
    dim3 qkvgrd(3 * DIM / BN, (BB * SS) / BM);   // (24, 32)
    gemm_t<1><<<qkvgrd, 256, 0, stream>>>(Xhi, nullptr, Wt3hi, nullptr, bq, bk, bv,
                                          Qw, Kw, Vt, nullptr, 1);

    dim3 agrd(SS / 128, BB * NH, 2);             // (16, 32, 2) = 1024 blocks
    flash_split<<<agrd, 256, 0, stream>>>(Qw, Kw, Vt, mask, Op0, Op1, lp0, lp1);

    combine<<<dim3(2048), 256, 0, stream>>>(Op0, Op1, lp0, lp1, Xhi, Xlo);

    // output projection: keep 3-term split precision (feeds fp32 output)
    dim3 ogrd(DIM / BN, (BB * SS) / BM);         // (8, 32)
    gemm_t<3><<<ogrd, 256, 0, stream>>>(Xhi, Xlo, Wothi, Wotlo, bo, nullptr, nullptr,
                                        nullptr, nullptr, nullptr, out, 0);
}

// Round 10
// 258.105 us; speedup vs baseline: 2.2584x; 1.0951x over previous
//
#include <hip/hip_runtime.h>
#include <hip/hip_bf16.h>
#include <math.h>

#define BB 2
#define SS 2048
#define DIM 1024
#define NH 16
#define DH 64

typedef __bf16 bf16x8 __attribute__((ext_vector_type(8)));
typedef float f32x4 __attribute__((ext_vector_type(4)));

__device__ __forceinline__ void glds16(const __hip_bfloat16* g, __hip_bfloat16* l) {
    __builtin_amdgcn_global_load_lds(
        (const __attribute__((address_space(1))) void*)g,
        (__attribute__((address_space(3))) void*)l, 16, 0, 0);
}

// fast fp32 -> bf16 (round-half-up, finite inputs)
__device__ __forceinline__ unsigned short f2bf(float x) {
    unsigned int u = __builtin_bit_cast(unsigned int, x);
    return (unsigned short)((u + 0x8000u) >> 16);
}

// pack two fp32 -> two bf16 in one register (hw op when available)
__device__ __forceinline__ unsigned int pk2bf(float a, float b) {
#if __has_builtin(__builtin_amdgcn_cvt_pk_bf16_f32)
    typedef __bf16 bf16x2 __attribute__((ext_vector_type(2)));
    bf16x2 p = __builtin_amdgcn_cvt_pk_bf16_f32(a, b);
    return __builtin_bit_cast(unsigned int, p);
#else
    return (unsigned int)f2bf(a) | ((unsigned int)f2bf(b) << 16);
#endif
}

// ---------------- prep: cast fp32 -> bf16 ----------------
__global__ void cast_bf16(const float4* __restrict__ in, ushort4* __restrict__ o) {
    int i = blockIdx.x * 256 + threadIdx.x;
    float4 v = in[i];
    ushort4 h;
    h.x = f2bf(v.x); h.y = f2bf(v.y); h.z = f2bf(v.z); h.w = f2bf(v.w);
    o[i] = h;
}

// ------- prep: transpose all 4 W [K,N] -> [N,K] bf16 (one launch) -------
__global__ void trans4(const float* __restrict__ Wq, const float* __restrict__ Wk,
                       const float* __restrict__ Wv, const float* __restrict__ Wo,
                       __hip_bfloat16* __restrict__ T4) {
    int z = blockIdx.z;
    const float* W = (z == 0) ? Wq : (z == 1) ? Wk : (z == 2) ? Wv : Wo;
    __hip_bfloat16* Thi = T4 + (size_t)z * DIM * DIM;
    __shared__ float tile[32][33];
    int k0 = blockIdx.x * 32, n0 = blockIdx.y * 32;
    int t = threadIdx.x;
    int r = t >> 3, c = (t & 7) << 2;
    float4 v = *(const float4*)&W[(size_t)(k0 + r) * DIM + n0 + c];
    tile[r][c] = v.x; tile[r][c + 1] = v.y; tile[r][c + 2] = v.z; tile[r][c + 3] = v.w;
    __syncthreads();
    size_t base = (size_t)(n0 + r) * DIM + k0 + c;
#pragma unroll
    for (int i = 0; i < 4; ++i)
        ((unsigned short*)Thi)[base + i] = f2bf(tile[c + i][r]);
}

// ------------- bf16 MFMA GEMM, 128x128 tile (m103 config, 1-term) -------------
// mode 0: of32[m*1024+n] = acc + b0[n]
// mode 1: fused QKV, N=3072: n<1024 -> Q split-heads, <2048 -> K split-heads,
//         else V^T [B,H,DH,S]
#define BM 128
#define BN 128
#define BK 32
__global__ __launch_bounds__(256) void gemm_bf(
    const __hip_bfloat16* __restrict__ A, const __hip_bfloat16* __restrict__ B,
    const float* __restrict__ b0, const float* __restrict__ b1, const float* __restrict__ b2,
    __hip_bfloat16* __restrict__ oq, __hip_bfloat16* __restrict__ ok,
    __hip_bfloat16* __restrict__ ov, float* __restrict__ of32, int mode) {
    __shared__ alignas(16) __hip_bfloat16 sA[BM * BK];
    __shared__ alignas(16) __hip_bfloat16 sB[BN * BK];
    const int K = 1024;
    int tid = threadIdx.x;
    int wave = tid >> 6, lane = tid & 63, quad = lane >> 4, l16 = lane & 15;
    int m0 = blockIdx.y * BM, n0 = blockIdx.x * BN;
    int mo = (wave >> 1) * 64, no = (wave & 1) * 64;

    f32x4 acc[4][4];
#pragma unroll
    for (int i = 0; i < 4; ++i)
#pragma unroll
        for (int j = 0; j < 4; ++j) acc[i][j] = (f32x4){0.f, 0.f, 0.f, 0.f};

    int ar = tid >> 2;
    int ac = (tid & 3) << 3;
    const __hip_bfloat16* gA = A + (size_t)(m0 + ar) * K + ac;
    const __hip_bfloat16* gB = B + (size_t)(n0 + ar) * K + ac;

    for (int k0 = 0; k0 < K; k0 += BK) {
        __syncthreads();
        glds16(gA + k0, &sA[ar * BK + ac]);
        glds16(gA + (size_t)64 * K + k0, &sA[(ar + 64) * BK + ac]);
        glds16(gB + k0, &sB[ar * BK + ac]);
        glds16(gB + (size_t)64 * K + k0, &sB[(ar + 64) * BK + ac]);
        __syncthreads();

        bf16x8 a_h[4], b_h[4];
#pragma unroll
        for (int i = 0; i < 4; ++i)
            a_h[i] = *(const bf16x8*)&sA[(mo + i * 16 + l16) * BK + quad * 8];
#pragma unroll
        for (int j = 0; j < 4; ++j)
            b_h[j] = *(const bf16x8*)&sB[(no + j * 16 + l16) * BK + quad * 8];
#pragma unroll
        for (int i = 0; i < 4; ++i)
#pragma unroll
            for (int j = 0; j < 4; ++j)
                acc[i][j] = __builtin_amdgcn_mfma_f32_16x16x32_bf16(a_h[i], b_h[j], acc[i][j], 0, 0, 0);
    }

    int which = (mode == 1) ? (n0 >> 10) : 0;
    const float* bp = (mode == 0) ? b0 : (which == 0) ? b0 : (which == 1) ? b1 : b2;
#pragma unroll
    for (int i = 0; i < 4; ++i)
#pragma unroll
        for (int j = 0; j < 4; ++j) {
            int gmb = m0 + mo + i * 16 + quad * 4;
            int gn  = n0 + no + j * 16 + l16;
            int nn  = gn & 1023;
            float bb = bp[(mode == 0) ? gn : nn];
#pragma unroll
            for (int r = 0; r < 4; ++r) {
                int gm = gmb + r;
                float v = acc[i][j][r] + bb;
                if (mode == 0) {
                    of32[(size_t)gm * 1024 + gn] = v;
                } else {
                    int b = gm >> 11, s = gm & 2047, h = nn >> 6, d = nn & 63;
                    if (which == 0)
                        ((unsigned short*)oq)[(((size_t)(b * NH + h)) * SS + s) * DH + d] = f2bf(v);
                    else if (which == 1)
                        ((unsigned short*)ok)[(((size_t)(b * NH + h)) * SS + s) * DH + d] = f2bf(v);
                    else
                        ((unsigned short*)ov)[(((size_t)(b * NH + h)) * DH + d) * SS + s] = f2bf(v);
                }
            }
        }
}

// ----- flash v7: 128-query tile, 64-key step, shared LDS staging, pk-pack -----
#define PSTR 68
__global__ __launch_bounds__(256) void flash_split(
        const __hip_bfloat16* __restrict__ Q,
        const __hip_bfloat16* __restrict__ K,
        const __hip_bfloat16* __restrict__ Vt,
        const float* __restrict__ mask,
        __hip_bfloat16* __restrict__ Op0, __hip_bfloat16* __restrict__ Op1,
        float* __restrict__ lp0, float* __restrict__ lp1) {
    int bh = blockIdx.y;
    int b = bh >> 4, h = bh & (NH - 1);
    int q0 = blockIdx.x * 128;
    int z  = blockIdx.z;
    __hip_bfloat16* Op = z ? Op1 : Op0;
    float*          lp = z ? lp1 : lp0;
    int tid = threadIdx.x;
    int wave = tid >> 6, lane = tid & 63, quad = lane >> 4, l16 = lane & 15;

    __shared__ alignas(16) __hip_bfloat16 sK[2][64 * 32];
    __shared__ alignas(16) __hip_bfloat16 sV[2][64 * 32];
    __shared__ __hip_bfloat16 Pl[4][32][PSTR];

    const float SC  = 0.125f * 1.44269504f;
    const float PEN = 1000000.0f * 1.44269504f;

    bf16x8 aq[2][2];
#pragma unroll
    for (int g = 0; g < 2; ++g) {
        const __hip_bfloat16* Qrow =
            Q + ((size_t)bh * SS + q0 + wave * 32 + g * 16 + l16) * DH;
        aq[g][0] = *(const bf16x8*)(Qrow + quad * 8);
        aq[g][1] = *(const bf16x8*)(Qrow + 32 + quad * 8);
    }

    const __hip_bfloat16* Kbase = K + (size_t)bh * SS * DH;
    const __hip_bfloat16* Vbase = Vt + (size_t)bh * DH * SS;
    const float* mbase = mask + b * SS;

    bf16x8 vones;
#pragma unroll
    for (int j = 0; j < 8; ++j) vones[j] = (__bf16)1.0f;

    f32x4 O[2][4];
#pragma unroll
    for (int g = 0; g < 2; ++g)
#pragma unroll
        for (int i = 0; i < 4; ++i) O[g][i] = (f32x4){0.f, 0.f, 0.f, 0.f};
    f32x4 lacc[2] = {(f32x4){0.f, 0.f, 0.f, 0.f}, (f32x4){0.f, 0.f, 0.f, 0.f}};

    const int krow = tid >> 2;
    const int kq   = (tid & 3) << 3;

    const int kbeg = z * (SS / 2), kend = kbeg + SS / 2;
    for (int k0 = kbeg; k0 < kend; k0 += 64) {
        __syncthreads();
        glds16(Kbase + (size_t)(k0 + krow) * DH + kq,      &sK[0][krow * 32 + kq]);
        glds16(Kbase + (size_t)(k0 + krow) * DH + 32 + kq, &sK[1][krow * 32 + kq]);
        glds16(Vbase + (size_t)krow * SS + k0 + kq,        &sV[0][krow * 32 + kq]);
        glds16(Vbase + (size_t)krow * SS + k0 + 32 + kq,   &sV[1][krow * 32 + kq]);
        __syncthreads();

#pragma unroll
        for (int nb = 0; nb < 4; ++nb) {
            int roff = (nb * 16 + l16) * 32 + quad * 8;
            bf16x8 bk0 = *(const bf16x8*)&sK[0][roff];
            bf16x8 bk1 = *(const bf16x8*)&sK[1][roff];
            float pen = PEN * (1.0f - mbase[k0 + nb * 16 + l16]);
#pragma unroll
            for (int g = 0; g < 2; ++g) {
                f32x4 s = (f32x4){0.f, 0.f, 0.f, 0.f};
                s = __builtin_amdgcn_mfma_f32_16x16x32_bf16(aq[g][0], bk0, s, 0, 0, 0);
                s = __builtin_amdgcn_mfma_f32_16x16x32_bf16(aq[g][1], bk1, s, 0, 0, 0);
                float e0 = exp2f(s[0] * SC - pen);
                float e1 = exp2f(s[1] * SC - pen);
                float e2 = exp2f(s[2] * SC - pen);
                float e3 = exp2f(s[3] * SC - pen);
                unsigned int p01 = pk2bf(e0, e1);
                unsigned int p23 = pk2bf(e2, e3);
                unsigned short* pr = (unsigned short*)&Pl[wave][g * 16 + quad * 4][nb * 16 + l16];
                pr[0]         = (unsigned short)p01;
                pr[PSTR]      = (unsigned short)(p01 >> 16);
                pr[2 * PSTR]  = (unsigned short)p23;
                pr[3 * PSTR]  = (unsigned short)(p23 >> 16);
            }
        }
#pragma unroll
        for (int c = 0; c < 2; ++c) {
            bf16x8 ap0 = *(const bf16x8*)(&Pl[wave][l16][c * 32 + quad * 8]);
            bf16x8 ap1 = *(const bf16x8*)(&Pl[wave][16 + l16][c * 32 + quad * 8]);
            lacc[0] = __builtin_amdgcn_mfma_f32_16x16x32_bf16(ap0, vones, lacc[0], 0, 0, 0);
            lacc[1] = __builtin_amdgcn_mfma_f32_16x16x32_bf16(ap1, vones, lacc[1], 0, 0, 0);
#pragma unroll
            for (int nb2 = 0; nb2 < 4; ++nb2) {
                bf16x8 bv = *(const bf16x8*)&sV[c][(nb2 * 16 + l16) * 32 + quad * 8];
                O[0][nb2] = __builtin_amdgcn_mfma_f32_16x16x32_bf16(ap0, bv, O[0][nb2], 0, 0, 0);
                O[1][nb2] = __builtin_amdgcn_mfma_f32_16x16x32_bf16(ap1, bv, O[1][nb2], 0, 0, 0);
            }
        }
    }
#pragma unroll
    for (int g = 0; g < 2; ++g) {
#pragma unroll
        for (int nb2 = 0; nb2 < 4; ++nb2)
#pragma unroll
            for (int r = 0; r < 4; ++r) {
                size_t row = (size_t)b * SS + q0 + wave * 32 + g * 16 + quad * 4 + r;
                ((unsigned short*)Op)[row * (NH * DH) + h * DH + nb2 * 16 + l16] =
                    f2bf(O[g][nb2][r]);
            }
        if (l16 == 0) {
#pragma unroll
            for (int r = 0; r < 4; ++r)
                lp[(size_t)bh * SS + q0 + wave * 32 + g * 16 + quad * 4 + r] = lacc[g][r];
        }
    }
}

// -------- combine: ctx = (O1+O2)/(l1+l2), bf16 --------
__global__ __launch_bounds__(256) void combine(
        const __hip_bfloat16* __restrict__ O1, const __hip_bfloat16* __restrict__ O2,
        const float* __restrict__ l1, const float* __restrict__ l2,
        __hip_bfloat16* __restrict__ ctx) {
    int i = blockIdx.x * 256 + threadIdx.x;
    size_t base = (size_t)i * 8;
    int row = i >> 7;
    int h   = (i >> 3) & 15;
    int b = row >> 11, s = row & 2047;
    size_t bhq = ((size_t)(b * NH + h)) * SS + s;
    float linv = 1.0f / (l1[bhq] + l2[bhq]);
    bf16x8 a = *(const bf16x8*)(O1 + base);
    bf16x8 c = *(const bf16x8*)(O2 + base);
    ushort4 o0, o1;
    o0.x = f2bf(((float)a[0] + (float)c[0]) * linv);
    o0.y = f2bf(((float)a[1] + (float)c[1]) * linv);
    o0.z = f2bf(((float)a[2] + (float)c[2]) * linv);
    o0.w = f2bf(((float)a[3] + (float)c[3]) * linv);
    o1.x = f2bf(((float)a[4] + (float)c[4]) * linv);
    o1.y = f2bf(((float)a[5] + (float)c[5]) * linv);
    o1.z = f2bf(((float)a[6] + (float)c[6]) * linv);
    o1.w = f2bf(((float)a[7] + (float)c[7]) * linv);
    ((ushort4*)(ctx + base))[0] = o0;
    ((ushort4*)(ctx + base + 4))[0] = o1;
}

extern "C" void kernel_launch(void* const* d_in, const int* in_sizes, int n_in,
                              void* d_out, int out_size, void* d_ws, size_t ws_size,
                              hipStream_t stream) {
    const float* X    = (const float*)d_in[0];
    const float* mask = (const float*)d_in[1];
    const float* Wq   = (const float*)d_in[2];
    const float* bq   = (const float*)d_in[3];
    const float* Wk   = (const float*)d_in[4];
    const float* bk   = (const float*)d_in[5];
    const float* Wv   = (const float*)d_in[6];
    const float* bv   = (const float*)d_in[7];
    const float* Wo   = (const float*)d_in[8];
    const float* bo   = (const float*)d_in[9];
    float* out = (float*)d_out;

    const size_t MB = 1u << 20;
    char* ws = (char*)d_ws;
    __hip_bfloat16* Xbf = (__hip_bfloat16*)(ws);             // 0-8   (later ctx)
    __hip_bfloat16* Op0 = (__hip_bfloat16*)(ws + 8 * MB);    // 8-16
    __hip_bfloat16* Wt4 = (__hip_bfloat16*)(ws + 16 * MB);   // 16-24 (Wq,Wk,Wv,Wo ^T)
    float*          lp0 = (float*)(ws + 24 * MB);            // 24-24.25
    float*          lp1 = (float*)(ws + 25 * MB);            // 25-25.25
    __hip_bfloat16* Qw  = (__hip_bfloat16*)(ws + 32 * MB);   // 32-40
    __hip_bfloat16* Kw  = (__hip_bfloat16*)(ws + 40 * MB);   // 40-48
    __hip_bfloat16* Vt  = (__hip_bfloat16*)(ws + 48 * MB);   // 48-56
    __hip_bfloat16* Op1 = (__hip_bfloat16*)(ws + 56 * MB);   // 56-64
    __hip_bfloat16* Wot = Wt4 + (size_t)3 * DIM * DIM;       // 22-24

    cast_bf16<<<4096, 256, 0, stream>>>((const float4*)X, (ushort4*)Xbf);

    dim3 tgrd(32, 32, 4);
    trans4<<<tgrd, 256, 0, stream>>>(Wq, Wk, Wv, Wo, Wt4);

    dim3 qkvgrd(3 * DIM / BN, (BB * SS) / BM);   // (24, 32)
    gemm_bf<<<qkvgrd, 256, 0, stream>>>(Xbf, Wt4, bq, bk, bv,
                                        Qw, Kw, Vt, nullptr, 1);

    dim3 agrd(SS / 128, BB * NH, 2);             // (16, 32, 2) = 1024 blocks
    flash_split<<<agrd, 256, 0, stream>>>(Qw, Kw, Vt, mask, Op0, Op1, lp0, lp1);

    // ctx overwrites Xbf (dead after QKV GEMM)
    combine<<<dim3(2048), 256, 0, stream>>>(Op0, Op1, lp0, lp1, Xbf);

    dim3 ogrd(DIM / BN, (BB * SS) / BM);         // (8, 32)
    gemm_bf<<<ogrd, 256, 0, stream>>>(Xbf, Wot, bo, nullptr, nullptr,
                                      nullptr, nullptr, nullptr, out, 0);
}

// Round 11
// 256.441 us; speedup vs baseline: 2.2730x; 1.0065x over previous
//
#include <hip/hip_runtime.h>
#include <hip/hip_bf16.h>
#include <math.h>

#define BB 2
#define SS 2048
#define DIM 1024
#define NH 16
#define DH 64

typedef __bf16 bf16x8 __attribute__((ext_vector_type(8)));
typedef float f32x4 __attribute__((ext_vector_type(4)));

__device__ __forceinline__ void glds16(const __hip_bfloat16* g, __hip_bfloat16* l) {
    __builtin_amdgcn_global_load_lds(
        (const __attribute__((address_space(1))) void*)g,
        (__attribute__((address_space(3))) void*)l, 16, 0, 0);
}

// fast fp32 -> bf16 (round-half-up, finite inputs)
__device__ __forceinline__ unsigned short f2bf(float x) {
    unsigned int u = __builtin_bit_cast(unsigned int, x);
    return (unsigned short)((u + 0x8000u) >> 16);
}

// pack two fp32 -> two bf16 in one register (hw op when available)
__device__ __forceinline__ unsigned int pk2bf(float a, float b) {
#if __has_builtin(__builtin_amdgcn_cvt_pk_bf16_f32)
    typedef __bf16 bf16x2 __attribute__((ext_vector_type(2)));
    bf16x2 p = __builtin_amdgcn_cvt_pk_bf16_f32(a, b);
    return __builtin_bit_cast(unsigned int, p);
#else
    return (unsigned int)f2bf(a) | ((unsigned int)f2bf(b) << 16);
#endif
}

// ------- prep (fused): z<4 -> transpose W[z] [K,N]->[N,K] bf16; z==4 -> cast X -------
__global__ void prep(const float* __restrict__ X,
                     const float* __restrict__ Wq, const float* __restrict__ Wk,
                     const float* __restrict__ Wv, const float* __restrict__ Wo,
                     __hip_bfloat16* __restrict__ T4, ushort4* __restrict__ Xbf) {
    int z = blockIdx.z;
    int t = threadIdx.x;
    if (z == 4) {
        // cast X: 1024 blocks (bx + by*32), 4096 floats each
        int c = blockIdx.y * 32 + blockIdx.x;
        const float4* in = (const float4*)X;
#pragma unroll
        for (int k = 0; k < 4; ++k) {
            int i = c * 1024 + k * 256 + t;
            float4 v = in[i];
            ushort4 h;
            h.x = f2bf(v.x); h.y = f2bf(v.y); h.z = f2bf(v.z); h.w = f2bf(v.w);
            Xbf[i] = h;
        }
        return;
    }
    const float* W = (z == 0) ? Wq : (z == 1) ? Wk : (z == 2) ? Wv : Wo;
    __hip_bfloat16* Thi = T4 + (size_t)z * DIM * DIM;
    __shared__ float tile[32][33];
    int k0 = blockIdx.x * 32, n0 = blockIdx.y * 32;
    int r = t >> 3, c = (t & 7) << 2;
    float4 v = *(const float4*)&W[(size_t)(k0 + r) * DIM + n0 + c];
    tile[r][c] = v.x; tile[r][c + 1] = v.y; tile[r][c + 2] = v.z; tile[r][c + 3] = v.w;
    __syncthreads();
    size_t base = (size_t)(n0 + r) * DIM + k0 + c;
#pragma unroll
    for (int i = 0; i < 4; ++i)
        ((unsigned short*)Thi)[base + i] = f2bf(tile[c + i][r]);
}

// ------------- bf16 MFMA GEMM, 128x128 tile (1-term) -------------
// mode 0: of32[m*1024+n] = acc + b0[n]
// mode 1: fused QKV, N=3072: n<1024 -> Q split-heads (PRE-SCALED by SC),
//         <2048 -> K split-heads, else V^T [B,H,DH,S]
#define BM 128
#define BN 128
#define BK 32
#define QSCALE (0.125f * 1.44269504f)   // fold softmax scale + log2e into Q
__global__ __launch_bounds__(256) void gemm_bf(
    const __hip_bfloat16* __restrict__ A, const __hip_bfloat16* __restrict__ B,
    const float* __restrict__ b0, const float* __restrict__ b1, const float* __restrict__ b2,
    __hip_bfloat16* __restrict__ oq, __hip_bfloat16* __restrict__ ok,
    __hip_bfloat16* __restrict__ ov, float* __restrict__ of32, int mode) {
    __shared__ alignas(16) __hip_bfloat16 sA[BM * BK];
    __shared__ alignas(16) __hip_bfloat16 sB[BN * BK];
    const int K = 1024;
    int tid = threadIdx.x;
    int wave = tid >> 6, lane = tid & 63, quad = lane >> 4, l16 = lane & 15;
    int m0 = blockIdx.y * BM, n0 = blockIdx.x * BN;
    int mo = (wave >> 1) * 64, no = (wave & 1) * 64;

    f32x4 acc[4][4];
#pragma unroll
    for (int i = 0; i < 4; ++i)
#pragma unroll
        for (int j = 0; j < 4; ++j) acc[i][j] = (f32x4){0.f, 0.f, 0.f, 0.f};

    int ar = tid >> 2;
    int ac = (tid & 3) << 3;
    const __hip_bfloat16* gA = A + (size_t)(m0 + ar) * K + ac;
    const __hip_bfloat16* gB = B + (size_t)(n0 + ar) * K + ac;

    for (int k0 = 0; k0 < K; k0 += BK) {
        __syncthreads();
        glds16(gA + k0, &sA[ar * BK + ac]);
        glds16(gA + (size_t)64 * K + k0, &sA[(ar + 64) * BK + ac]);
        glds16(gB + k0, &sB[ar * BK + ac]);
        glds16(gB + (size_t)64 * K + k0, &sB[(ar + 64) * BK + ac]);
        __syncthreads();

        bf16x8 a_h[4], b_h[4];
#pragma unroll
        for (int i = 0; i < 4; ++i)
            a_h[i] = *(const bf16x8*)&sA[(mo + i * 16 + l16) * BK + quad * 8];
#pragma unroll
        for (int j = 0; j < 4; ++j)
            b_h[j] = *(const bf16x8*)&sB[(no + j * 16 + l16) * BK + quad * 8];
#pragma unroll
        for (int i = 0; i < 4; ++i)
#pragma unroll
            for (int j = 0; j < 4; ++j)
                acc[i][j] = __builtin_amdgcn_mfma_f32_16x16x32_bf16(a_h[i], b_h[j], acc[i][j], 0, 0, 0);
    }

    int which = (mode == 1) ? (n0 >> 10) : 0;
    const float* bp = (mode == 0) ? b0 : (which == 0) ? b0 : (which == 1) ? b1 : b2;
#pragma unroll
    for (int i = 0; i < 4; ++i)
#pragma unroll
        for (int j = 0; j < 4; ++j) {
            int gmb = m0 + mo + i * 16 + quad * 4;
            int gn  = n0 + no + j * 16 + l16;
            int nn  = gn & 1023;
            float bb = bp[(mode == 0) ? gn : nn];
#pragma unroll
            for (int r = 0; r < 4; ++r) {
                int gm = gmb + r;
                float v = acc[i][j][r] + bb;
                if (mode == 0) {
                    of32[(size_t)gm * 1024 + gn] = v;
                } else {
                    int b = gm >> 11, s = gm & 2047, h = nn >> 6, d = nn & 63;
                    if (which == 0)
                        ((unsigned short*)oq)[(((size_t)(b * NH + h)) * SS + s) * DH + d] = f2bf(v * QSCALE);
                    else if (which == 1)
                        ((unsigned short*)ok)[(((size_t)(b * NH + h)) * SS + s) * DH + d] = f2bf(v);
                    else
                        ((unsigned short*)ov)[(((size_t)(b * NH + h)) * DH + d) * SS + s] = f2bf(v);
                }
            }
        }
}

// ----- flash v8: 128-query tile, 64-key step, shared LDS staging, pre-scaled Q -----
#define PSTR 68
__global__ __launch_bounds__(256) void flash_split(
        const __hip_bfloat16* __restrict__ Q,
        const __hip_bfloat16* __restrict__ K,
        const __hip_bfloat16* __restrict__ Vt,
        const float* __restrict__ mask,
        __hip_bfloat16* __restrict__ Op0, __hip_bfloat16* __restrict__ Op1,
        float* __restrict__ lp0, float* __restrict__ lp1) {
    int bh = blockIdx.y;
    int b = bh >> 4, h = bh & (NH - 1);
    int q0 = blockIdx.x * 128;
    int z  = blockIdx.z;
    __hip_bfloat16* Op = z ? Op1 : Op0;
    float*          lp = z ? lp1 : lp0;
    int tid = threadIdx.x;
    int wave = tid >> 6, lane = tid & 63, quad = lane >> 4, l16 = lane & 15;

    __shared__ alignas(16) __hip_bfloat16 sK[2][64 * 32];
    __shared__ alignas(16) __hip_bfloat16 sV[2][64 * 32];
    __shared__ __hip_bfloat16 Pl[4][32][PSTR];

    const float PEN = 1000000.0f * 1.44269504f;

    bf16x8 aq[2][2];
#pragma unroll
    for (int g = 0; g < 2; ++g) {
        const __hip_bfloat16* Qrow =
            Q + ((size_t)bh * SS + q0 + wave * 32 + g * 16 + l16) * DH;
        aq[g][0] = *(const bf16x8*)(Qrow + quad * 8);
        aq[g][1] = *(const bf16x8*)(Qrow + 32 + quad * 8);
    }

    const __hip_bfloat16* Kbase = K + (size_t)bh * SS * DH;
    const __hip_bfloat16* Vbase = Vt + (size_t)bh * DH * SS;
    const float* mbase = mask + b * SS;

    bf16x8 vones;
#pragma unroll
    for (int j = 0; j < 8; ++j) vones[j] = (__bf16)1.0f;

    f32x4 O[2][4];
#pragma unroll
    for (int g = 0; g < 2; ++g)
#pragma unroll
        for (int i = 0; i < 4; ++i) O[g][i] = (f32x4){0.f, 0.f, 0.f, 0.f};
    f32x4 lacc[2] = {(f32x4){0.f, 0.f, 0.f, 0.f}, (f32x4){0.f, 0.f, 0.f, 0.f}};

    const int krow = tid >> 2;
    const int kq   = (tid & 3) << 3;

    const int kbeg = z * (SS / 2), kend = kbeg + SS / 2;
    for (int k0 = kbeg; k0 < kend; k0 += 64) {
        __syncthreads();
        glds16(Kbase + (size_t)(k0 + krow) * DH + kq,      &sK[0][krow * 32 + kq]);
        glds16(Kbase + (size_t)(k0 + krow) * DH + 32 + kq, &sK[1][krow * 32 + kq]);
        glds16(Vbase + (size_t)krow * SS + k0 + kq,        &sV[0][krow * 32 + kq]);
        glds16(Vbase + (size_t)krow * SS + k0 + 32 + kq,   &sV[1][krow * 32 + kq]);
        __syncthreads();

#pragma unroll
        for (int nb = 0; nb < 4; ++nb) {
            int roff = (nb * 16 + l16) * 32 + quad * 8;
            bf16x8 bk0 = *(const bf16x8*)&sK[0][roff];
            bf16x8 bk1 = *(const bf16x8*)&sK[1][roff];
            float pen = PEN * (1.0f - mbase[k0 + nb * 16 + l16]);
#pragma unroll
            for (int g = 0; g < 2; ++g) {
                f32x4 s = (f32x4){0.f, 0.f, 0.f, 0.f};
                s = __builtin_amdgcn_mfma_f32_16x16x32_bf16(aq[g][0], bk0, s, 0, 0, 0);
                s = __builtin_amdgcn_mfma_f32_16x16x32_bf16(aq[g][1], bk1, s, 0, 0, 0);
                // Q pre-scaled: score already in log2 domain
                float e0 = exp2f(s[0] - pen);
                float e1 = exp2f(s[1] - pen);
                float e2 = exp2f(s[2] - pen);
                float e3 = exp2f(s[3] - pen);
                unsigned int p01 = pk2bf(e0, e1);
                unsigned int p23 = pk2bf(e2, e3);
                unsigned short* pr = (unsigned short*)&Pl[wave][g * 16 + quad * 4][nb * 16 + l16];
                pr[0]         = (unsigned short)p01;
                pr[PSTR]      = (unsigned short)(p01 >> 16);
                pr[2 * PSTR]  = (unsigned short)p23;
                pr[3 * PSTR]  = (unsigned short)(p23 >> 16);
            }
        }
#pragma unroll
        for (int c = 0; c < 2; ++c) {
            bf16x8 ap0 = *(const bf16x8*)(&Pl[wave][l16][c * 32 + quad * 8]);
            bf16x8 ap1 = *(const bf16x8*)(&Pl[wave][16 + l16][c * 32 + quad * 8]);
            lacc[0] = __builtin_amdgcn_mfma_f32_16x16x32_bf16(ap0, vones, lacc[0], 0, 0, 0);
            lacc[1] = __builtin_amdgcn_mfma_f32_16x16x32_bf16(ap1, vones, lacc[1], 0, 0, 0);
#pragma unroll
            for (int nb2 = 0; nb2 < 4; ++nb2) {
                bf16x8 bv = *(const bf16x8*)&sV[c][(nb2 * 16 + l16) * 32 + quad * 8];
                O[0][nb2] = __builtin_amdgcn_mfma_f32_16x16x32_bf16(ap0, bv, O[0][nb2], 0, 0, 0);
                O[1][nb2] = __builtin_amdgcn_mfma_f32_16x16x32_bf16(ap1, bv, O[1][nb2], 0, 0, 0);
            }
        }
    }
#pragma unroll
    for (int g = 0; g < 2; ++g) {
#pragma unroll
        for (int nb2 = 0; nb2 < 4; ++nb2)
#pragma unroll
            for (int r = 0; r < 4; ++r) {
                size_t row = (size_t)b * SS + q0 + wave * 32 + g * 16 + quad * 4 + r;
                ((unsigned short*)Op)[row * (NH * DH) + h * DH + nb2 * 16 + l16] =
                    f2bf(O[g][nb2][r]);
            }
        if (l16 == 0) {
#pragma unroll
            for (int r = 0; r < 4; ++r)
                lp[(size_t)bh * SS + q0 + wave * 32 + g * 16 + quad * 4 + r] = lacc[g][r];
        }
    }
}

// -------- combine: ctx = (O1+O2)/(l1+l2), bf16 --------
__global__ __launch_bounds__(256) void combine(
        const __hip_bfloat16* __restrict__ O1, const __hip_bfloat16* __restrict__ O2,
        const float* __restrict__ l1, const float* __restrict__ l2,
        __hip_bfloat16* __restrict__ ctx) {
    int i = blockIdx.x * 256 + threadIdx.x;
    size_t base = (size_t)i * 8;
    int row = i >> 7;
    int h   = (i >> 3) & 15;
    int b = row >> 11, s = row & 2047;
    size_t bhq = ((size_t)(b * NH + h)) * SS + s;
    float linv = 1.0f / (l1[bhq] + l2[bhq]);
    bf16x8 a = *(const bf16x8*)(O1 + base);
    bf16x8 c = *(const bf16x8*)(O2 + base);
    ushort4 o0, o1;
    o0.x = f2bf(((float)a[0] + (float)c[0]) * linv);
    o0.y = f2bf(((float)a[1] + (float)c[1]) * linv);
    o0.z = f2bf(((float)a[2] + (float)c[2]) * linv);
    o0.w = f2bf(((float)a[3] + (float)c[3]) * linv);
    o1.x = f2bf(((float)a[4] + (float)c[4]) * linv);
    o1.y = f2bf(((float)a[5] + (float)c[5]) * linv);
    o1.z = f2bf(((float)a[6] + (float)c[6]) * linv);
    o1.w = f2bf(((float)a[7] + (float)c[7]) * linv);
    ((ushort4*)(ctx + base))[0] = o0;
    ((ushort4*)(ctx + base + 4))[0] = o1;
}

extern "C" void kernel_launch(void* const* d_in, const int* in_sizes, int n_in,
                              void* d_out, int out_size, void* d_ws, size_t ws_size,
                              hipStream_t stream) {
    const float* X    = (const float*)d_in[0];
    const float* mask = (const float*)d_in[1];
    const float* Wq   = (const float*)d_in[2];
    const float* bq   = (const float*)d_in[3];
    const float* Wk   = (const float*)d_in[4];
    const float* bk   = (const float*)d_in[5];
    const float* Wv   = (const float*)d_in[6];
    const float* bv   = (const float*)d_in[7];
    const float* Wo   = (const float*)d_in[8];
    const float* bo   = (const float*)d_in[9];
    float* out = (float*)d_out;

    const size_t MB = 1u << 20;
    char* ws = (char*)d_ws;
    __hip_bfloat16* Xbf = (__hip_bfloat16*)(ws);             // 0-8   (later ctx)
    __hip_bfloat16* Op0 = (__hip_bfloat16*)(ws + 8 * MB);    // 8-16
    __hip_bfloat16* Wt4 = (__hip_bfloat16*)(ws + 16 * MB);   // 16-24 (Wq,Wk,Wv,Wo ^T)
    float*          lp0 = (float*)(ws + 24 * MB);            // 24-24.25
    float*          lp1 = (float*)(ws + 25 * MB);            // 25-25.25
    __hip_bfloat16* Qw  = (__hip_bfloat16*)(ws + 32 * MB);   // 32-40
    __hip_bfloat16* Kw  = (__hip_bfloat16*)(ws + 40 * MB);   // 40-48
    __hip_bfloat16* Vt  = (__hip_bfloat16*)(ws + 48 * MB);   // 48-56
    __hip_bfloat16* Op1 = (__hip_bfloat16*)(ws + 56 * MB);   // 56-64
    __hip_bfloat16* Wot = Wt4 + (size_t)3 * DIM * DIM;       // 22-24

    dim3 pgrd(32, 32, 5);
    prep<<<pgrd, 256, 0, stream>>>(X, Wq, Wk, Wv, Wo, Wt4, (ushort4*)Xbf);

    dim3 qkvgrd(3 * DIM / BN, (BB * SS) / BM);   // (24, 32)
    gemm_bf<<<qkvgrd, 256, 0, stream>>>(Xbf, Wt4, bq, bk, bv,
                                        Qw, Kw, Vt, nullptr, 1);

    dim3 agrd(SS / 128, BB * NH, 2);             // (16, 32, 2) = 1024 blocks
    flash_split<<<agrd, 256, 0, stream>>>(Qw, Kw, Vt, mask, Op0, Op1, lp0, lp1);

    // ctx overwrites Xbf (dead after QKV GEMM)
    combine<<<dim3(2048), 256, 0, stream>>>(Op0, Op1, lp0, lp1, Xbf);

    dim3 ogrd(DIM / BN, (BB * SS) / BM);         // (8, 32)
    gemm_bf<<<ogrd, 256, 0, stream>>>(Xbf, Wot, bo, nullptr, nullptr,
                                      nullptr, nullptr, nullptr, out, 0);
}